// Round 6
// baseline (321.628 us; speedup 1.0000x reference)
//
#include <hip/hip_runtime.h>
#include <hip/hip_bf16.h>
#include <math.h>

// Problem constants
#define DIMC   256      // DIM
#define DI     512      // D_INNER
#define DS     16       // D_STATE
#define DTR    16       // DT_RANK
#define NX     48       // DT_RANK + 2*D_STATE
#define BATCH  8
#define LSEQ   1024     // H*W
#define MROWS  8192     // BATCH*LSEQ
#define CHUNK  32       // scan chunk (32 -> 512 blocks for the d-per-lane scan)
#define NC     (LSEQ / CHUNK)   // 32 chunks

typedef __attribute__((ext_vector_type(8))) short short8;
typedef __attribute__((ext_vector_type(4))) float f32x4;

__device__ __forceinline__ unsigned short f2bf(float v) {
  __hip_bfloat16 h = __float2bfloat16(v);
  return *reinterpret_cast<unsigned short*>(&h);
}
__device__ __forceinline__ float bf2f(unsigned short u) {
  return __int_as_float(((int)u) << 16);
}

// Async global->LDS, 16B per lane. lds base must be wave-uniform; HW writes
// lane i's 16B to ldsbase + i*16 (m97 pattern).
__device__ __forceinline__ void load_lds16(const void* g, void* l) {
  __builtin_amdgcn_global_load_lds(
      (const __attribute__((address_space(1))) unsigned int*)g,
      (__attribute__((address_space(3))) unsigned int*)l, 16, 0, 0);
}

// Device-scope grid barrier. Co-residency is guaranteed by construction:
// scan_all is __launch_bounds__(256,2) (VGPR<=128 -> 2 blocks/CU) and uses
// 36KB LDS (<=4 blocks/CU), grid=512 on 256 CUs. Spin is BOUNDED so a
// broken barrier produces a wrong answer (absmax fail), never a hang.
__device__ __forceinline__ void gridbar(unsigned int* ctr, unsigned int nblk) {
  __syncthreads();
  if (threadIdx.x == 0) {
    __threadfence();   // release: publish this block's global writes
    __hip_atomic_fetch_add(ctr, 1u, __ATOMIC_ACQ_REL, __HIP_MEMORY_SCOPE_AGENT);
    for (int it = 0; it < (1 << 20); ++it) {
      if (__hip_atomic_load(ctr, __ATOMIC_ACQUIRE, __HIP_MEMORY_SCOPE_AGENT) >= nblk)
        break;
      __builtin_amdgcn_s_sleep(8);
    }
    __threadfence();   // acquire: invalidate stale cached lines
  }
  __syncthreads();
}

// ---------------------------------------------------------------------------
// Prologue: weight prep + LayerNorm in ONE launch (branch on blockIdx.x).
__global__ __launch_bounds__(256) void prologue(const float* __restrict__ W_in,
                                                const float* __restrict__ W_out,
                                                const float* __restrict__ W_xproj,
                                                const float* __restrict__ W_dt,
                                                const float* __restrict__ x,
                                                const float* __restrict__ gamma,
                                                const float* __restrict__ beta,
                                                unsigned short* __restrict__ Wib,
                                                unsigned short* __restrict__ Wob,
                                                unsigned short* __restrict__ Wxpb,
                                                unsigned short* __restrict__ Wdtb,
                                                unsigned short* __restrict__ xnb) {
  __shared__ float sx[DIMC][67];
  __shared__ float smean[64], srs[64];
  const int blk = blockIdx.x, tid = threadIdx.x;
  if (blk < 384) {
    float (*t)[67] = sx;
    const float* W; unsigned short* Wt; int K, N, bx, by;
    if (blk < 256) { W = W_in;  Wt = Wib; K = DIMC; N = 1024; bx = blk & 31; by = blk >> 5; }
    else           { W = W_out; Wt = Wob; K = DI;   N = DIMC; bx = (blk - 256) & 7; by = (blk - 256) >> 3; }
    int n0 = bx * 32, k0 = by * 32;
    int tx = tid & 31, ty = tid >> 5;
    for (int i = ty; i < 32; i += 8) t[i][tx] = W[(size_t)(k0 + i) * N + n0 + tx];
    __syncthreads();
    for (int i = ty; i < 32; i += 8)
      Wt[(size_t)(n0 + i) * K + k0 + tx] = f2bf(t[tx][i]);
    return;
  }
  if (blk < 512) {
    int idx = (blk - 384) * 256 + tid;   // < 64*512
    int n = idx >> 9, k = idx & 511;
    Wxpb[idx] = (n < NX) ? f2bf(W_xproj[(size_t)k * NX + n]) : (unsigned short)0;
    return;
  }
  if (blk < 576) {
    int idx = (blk - 512) * 256 + tid;   // < 512*32
    int n = idx >> 5, k = idx & 31;
    Wdtb[idx] = (k < DTR) ? f2bf(W_dt[(size_t)k * DI + n]) : (unsigned short)0;
    return;
  }
  // ---- LayerNorm ----
  const int lb = blk - 576;
  const int b = lb >> 4, l0 = (lb & 15) * 64;
  {
    const int cbase = tid >> 2;
    const int lp = (tid & 3) * 16;
#pragma unroll
    for (int cg = 0; cg < 4; ++cg) {
      const int c = cg * 64 + cbase;
      const float* p = x + ((size_t)b * DIMC + c) * LSEQ + l0 + lp;
#pragma unroll
      for (int q = 0; q < 4; ++q) {
        float4 v = *(const float4*)(p + q * 4);
        sx[c][lp + q * 4 + 0] = v.x;
        sx[c][lp + q * 4 + 1] = v.y;
        sx[c][lp + q * 4 + 2] = v.z;
        sx[c][lp + q * 4 + 3] = v.w;
      }
    }
  }
  __syncthreads();
  {
    const int lane = tid & 63, w = tid >> 6;
    const int l = (w << 4) + (lane & 15);
    const int quad = lane >> 4;
    float sum = 0.f, sq = 0.f;
#pragma unroll 8
    for (int cc = 0; cc < 64; ++cc) {
      float v = sx[quad * 64 + cc][l];
      sum += v; sq += v * v;
    }
    sum += __shfl_xor(sum, 16); sq += __shfl_xor(sq, 16);
    sum += __shfl_xor(sum, 32); sq += __shfl_xor(sq, 32);
    if (quad == 0) {
      float mean = sum * (1.f / 256.f);
      float var  = sq * (1.f / 256.f) - mean * mean;
      smean[l] = mean; srs[l] = rsqrtf(var + 1e-5f);
    }
  }
  __syncthreads();
  {
    const float gg = gamma[tid], bb = beta[tid];
    const size_t base = ((size_t)b * LSEQ + l0) * DIMC + tid;
#pragma unroll 4
    for (int ll = 0; ll < 64; ++ll) {
      float v = (sx[tid][ll] - smean[ll]) * srs[ll] * gg + bb;
      xnb[base + (size_t)ll * DIMC] = f2bf(v);
    }
  }
}

// ---------------------------------------------------------------------------
// bf16 MFMA GEMM, m97 structure: 128x128 tile, 4x4 acc/wave, BK=32.
// C(bf16 [M][N]) = A(bf16 [M][K]) * Bt(bf16 [N][K])^T.  (used for gemm1)
__global__ __launch_bounds__(256) void gemm_bf16_128(const unsigned short* __restrict__ A,
                                                     const unsigned short* __restrict__ Bt,
                                                     unsigned short* __restrict__ Cb,
                                                     int M, int N, int K) {
  __shared__ unsigned short As[128][32];
  __shared__ unsigned short Bs[128][32];
  const int tid = threadIdx.x;
  const int lane = tid & 63, wave = tid >> 6;
  const int wm = wave >> 1, wn = wave & 1;
  const int quad = lane >> 4, l16 = lane & 15;
  const int m0 = blockIdx.y * 128, n0 = blockIdx.x * 128;

  f32x4 acc[4][4];
#pragma unroll
  for (int i = 0; i < 4; ++i)
#pragma unroll
    for (int j = 0; j < 4; ++j) acc[i][j] = (f32x4){0.f, 0.f, 0.f, 0.f};

  for (int k0 = 0; k0 < K; k0 += 32) {
    // A tile: 512 chunks of 16B (2/thread); LDS offset = id*16 (linear).
#pragma unroll
    for (int q = 0; q < 2; ++q) {
      int id = q * 256 + tid;
      int row = id >> 2, c = id & 3;
      load_lds16(A + (size_t)(m0 + row) * K + k0 + c * 8,
                 (char*)&As[0][0] + (size_t)(q * 256 + wave * 64) * 16);
    }
    // B tile: 512 chunks (2/thread).
#pragma unroll
    for (int q = 0; q < 2; ++q) {
      int id = q * 256 + tid;
      int row = id >> 2, c = id & 3;
      load_lds16(Bt + (size_t)(n0 + row) * K + k0 + c * 8,
                 (char*)&Bs[0][0] + (size_t)(q * 256 + wave * 64) * 16);
    }
    __syncthreads();   // drains vmcnt before LDS reads
    short8 af[4], bfr[4];
#pragma unroll
    for (int i = 0; i < 4; ++i)
      af[i] = *(const short8*)&As[wm * 64 + i * 16 + l16][quad * 8];
#pragma unroll
    for (int j = 0; j < 4; ++j)
      bfr[j] = *(const short8*)&Bs[wn * 64 + j * 16 + l16][quad * 8];
#pragma unroll
    for (int i = 0; i < 4; ++i)
#pragma unroll
      for (int j = 0; j < 4; ++j)
        acc[i][j] = __builtin_amdgcn_mfma_f32_16x16x32_bf16(af[i], bfr[j], acc[i][j], 0, 0, 0);
    __syncthreads();
  }

#pragma unroll
  for (int i = 0; i < 4; ++i) {
    int rowb = wm * 64 + i * 16 + quad * 4;
#pragma unroll
    for (int j = 0; j < 4; ++j) {
      int n = n0 + wn * 64 + j * 16 + l16;
#pragma unroll
      for (int r = 0; r < 4; ++r)
        Cb[(size_t)(m0 + rowb + r) * N + n] = f2bf(acc[i][j][r]);
    }
  }
}

// ---------------------------------------------------------------------------
// bf16 MFMA GEMM: C = A(bf16 [M][K]) * Bt(bf16 [N][K])^T.  128x64 tile.
// mode 1: f32 out[b*DIMC*LSEQ + n*LSEQ + l] = acc + X  (transpose + residual)
#define GTM 128
#define GTN 64
#define GBK 32
__global__ __launch_bounds__(256) void gemm_bf16(const unsigned short* __restrict__ A,
                                                 const unsigned short* __restrict__ Bt,
                                                 void* __restrict__ Cout,
                                                 int M, int N, int K, int mode,
                                                 const float* __restrict__ X) {
  __shared__ unsigned short As[GTM][GBK];
  __shared__ unsigned short Bs[GTN][GBK];
  const int tid = threadIdx.x;
  const int lane = tid & 63, wave = tid >> 6;
  const int wm = wave >> 1, wn = wave & 1;
  const int quad = lane >> 4, l16 = lane & 15;
  const int m0 = blockIdx.y * GTM, n0 = blockIdx.x * GTN;

  f32x4 acc[4][2];
#pragma unroll
  for (int i = 0; i < 4; ++i)
#pragma unroll
    for (int j = 0; j < 2; ++j) acc[i][j] = (f32x4){0.f, 0.f, 0.f, 0.f};

  for (int k0 = 0; k0 < K; k0 += GBK) {
#pragma unroll
    for (int q = 0; q < 2; ++q) {
      int id = q * 256 + tid;
      int row = id >> 2, c = id & 3;
      load_lds16(A + (size_t)(m0 + row) * K + k0 + c * 8,
                 (char*)&As[0][0] + (size_t)(q * 256 + wave * 64) * 16);
    }
    {
      int row = tid >> 2, c = tid & 3;
      load_lds16(Bt + (size_t)(n0 + row) * K + k0 + c * 8,
                 (char*)&Bs[0][0] + (size_t)(wave * 64) * 16);
    }
    __syncthreads();   // drains vmcnt before LDS reads
    short8 af[4], bfrag[2];
#pragma unroll
    for (int i = 0; i < 4; ++i)
      af[i] = *(const short8*)&As[wm * 64 + i * 16 + l16][quad * 8];
#pragma unroll
    for (int j = 0; j < 2; ++j)
      bfrag[j] = *(const short8*)&Bs[wn * 32 + j * 16 + l16][quad * 8];
#pragma unroll
    for (int i = 0; i < 4; ++i)
#pragma unroll
      for (int j = 0; j < 2; ++j)
        acc[i][j] = __builtin_amdgcn_mfma_f32_16x16x32_bf16(af[i], bfrag[j], acc[i][j], 0, 0, 0);
    __syncthreads();
  }

  if (mode == 2) {
    unsigned short* Cb = (unsigned short*)Cout;
#pragma unroll
    for (int i = 0; i < 4; ++i) {
      int rowb = wm * 64 + i * 16 + quad * 4;
#pragma unroll
      for (int j = 0; j < 2; ++j) {
        int n = n0 + wn * 32 + j * 16 + l16;
#pragma unroll
        for (int r = 0; r < 4; ++r)
          Cb[(size_t)(m0 + rowb + r) * N + n] = f2bf(acc[i][j][r]);
      }
    }
  } else {
    float* C = (float*)Cout;
#pragma unroll
    for (int i = 0; i < 4; ++i) {
      int m = m0 + wm * 64 + i * 16 + quad * 4;
      int b = m >> 10, l = m & 1023;
#pragma unroll
      for (int j = 0; j < 2; ++j) {
        int n = n0 + wn * 32 + j * 16 + l16;
        size_t o = (size_t)b * (DIMC * LSEQ) + (size_t)n * LSEQ + l;
        f32x4 xv = *(const f32x4*)(X + o);
        f32x4 rv = acc[i][j] + xv;
        *(f32x4*)(C + o) = rv;
      }
    }
  }
}

// ---------------------------------------------------------------------------
// Fused conv + SiLU + xproj + dt (MFMA).
// m-tile 16, grid 512 (2 blocks/CU co-resident = 2 waves/SIMD).
// Also zeroes the scan grid-barrier counters (runs before scan in-stream).
__global__ __launch_bounds__(256) void conv_xproj_dt(
    const unsigned short* __restrict__ xzb,
    const float* __restrict__ conv_w,
    const float* __restrict__ conv_b,
    const unsigned short* __restrict__ Wxpb,
    const unsigned short* __restrict__ Wdtb,
    const float* __restrict__ b_dt,
    float* __restrict__ dbcBC,
    unsigned int* __restrict__ dtu,
    unsigned int* __restrict__ bar) {
  __shared__ unsigned short sxz[19][512];       // 16 rows + 3 halo
  __shared__ unsigned short su[16][512 + 8];
  __shared__ unsigned short sdbc[16][40];
  const int m0 = blockIdx.x * 16;
  const int l0 = m0 & 1023;
  const int tid = threadIdx.x, lane = tid & 63, w = tid >> 6;
  const int quad = lane >> 4, l16 = lane & 15;

  if (blockIdx.x == 0 && tid < 2) bar[tid] = 0u;

  // Stage the xz u-half tile with halo: 19*64 = 1216 chunks of 8 bf16.
#pragma unroll
  for (int q = 0; q < 5; ++q) {
    int id = q * 256 + tid;
    if (id < 19 * 64) {
      int rr = id >> 6, c8 = id & 63;
      uint4 v; v.x = 0u; v.y = 0u; v.z = 0u; v.w = 0u;
      if (l0 - 3 + rr >= 0)
        v = *(const uint4*)(xzb + (size_t)(m0 - 3 + rr) * 1024 + c8 * 8);
      *(uint4*)&sxz[rr][c8 * 8] = v;
    }
  }
  __syncthreads();

  // conv(k=4) + bias + SiLU -> su (32 outputs/thread, coalesced in c).
#pragma unroll 4
  for (int q = 0; q < 32; ++q) {
    int idx = q * 256 + tid;
    int r = idx >> 9, c = idx & 511;
    float4 wv = *(const float4*)(conv_w + c * 4);
    float acc = conv_b[c];
    acc = fmaf(bf2f(sxz[r + 0][c]), wv.x, acc);
    acc = fmaf(bf2f(sxz[r + 1][c]), wv.y, acc);
    acc = fmaf(bf2f(sxz[r + 2][c]), wv.z, acc);
    acc = fmaf(bf2f(sxz[r + 3][c]), wv.w, acc);
    float u = acc / (1.f + __expf(-acc));
    su[r][c] = f2bf(u);
  }
  __syncthreads();

  // xproj MFMA: A-frags from su, B-frags straight from global (L2-hot).
  f32x4 acc = (f32x4){0.f, 0.f, 0.f, 0.f};
#pragma unroll 4
  for (int k0 = 0; k0 < 512; k0 += 32) {
    short8 af = *(const short8*)&su[l16][k0 + quad * 8];
    short8 bf = *(const short8*)(Wxpb + (size_t)(w * 16 + l16) * 512 + k0 + quad * 8);
    acc = __builtin_amdgcn_mfma_f32_16x16x32_bf16(af, bf, acc, 0, 0, 0);
  }
  // Persist only B (n=16..31) and C (n=32..47) columns.
  if (w == 1 || w == 2) {
#pragma unroll
    for (int r = 0; r < 4; ++r)
      dbcBC[(size_t)(m0 + quad * 4 + r) * 32 + (w - 1) * 16 + l16] = acc[r];
  }
  if (w < 2) {
#pragma unroll
    for (int r = 0; r < 4; ++r)
      sdbc[quad * 4 + r][w * 16 + l16] = f2bf(acc[r]);
  }
  __syncthreads();

  // dt MFMA + softplus + dtu pack (u pulled from su).
  short8 af0 = *(const short8*)&sdbc[l16][quad * 8];
#pragma unroll
  for (int jn = 0; jn < 8; ++jn) {
    const int n0 = w * 128 + jn * 16;
    short8 bf = *(const short8*)(Wdtb + (size_t)(n0 + l16) * 32 + quad * 8);
    f32x4 a0 = (f32x4){0.f, 0.f, 0.f, 0.f};
    a0 = __builtin_amdgcn_mfma_f32_16x16x32_bf16(af0, bf, a0, 0, 0, 0);
    const float bd = b_dt[n0 + l16];
#pragma unroll
    for (int r = 0; r < 4; ++r) {
      int lr0 = quad * 4 + r;
      float v = a0[r] + bd;
      float sp = (v > 20.f) ? v : log1pf(__expf(v));
      unsigned int u0 = (unsigned int)su[lr0][n0 + l16];
      dtu[(size_t)(m0 + lr0) * DI + n0 + l16] = u0 | ((unsigned int)f2bf(sp) << 16);
    }
  }
}

// ---------------------------------------------------------------------------
// Fully fused chunked selective scan (single launch, 2 device-wide barriers).
// d-per-lane layout: thread owns one d-channel, 16 s-states in registers.
// Grid (BATCH, 2, NC) = 512 blocks. __launch_bounds__(256,2) caps VGPR at 128
// -> 2 blocks/CU guaranteed (LDS 36KB allows 4) -> all 512 blocks co-resident,
// so the grid barrier cannot deadlock.
//   phase 1: local scan from h=0 -> hend, Ssum
//   barrier; phase 2 (cc<16 blocks): serial chunk combine -> hin
//   barrier; phase 3: re-scan from hin, y dot + gate epilogue -> yb
__global__ __launch_bounds__(256, 2) void scan_all(
    const unsigned int* __restrict__ dtu,
    const float* __restrict__ dbcBC,
    const unsigned short* __restrict__ xzb,
    const float* __restrict__ A_log,
    const float* __restrict__ D_skip,
    float* __restrict__ hend,
    float* __restrict__ Ssum,
    float* __restrict__ hin,
    unsigned int* __restrict__ bar,
    unsigned short* __restrict__ yb) {
  const int bb = blockIdx.x, dh = blockIdx.y, cc = blockIdx.z;
  const int tid = threadIdx.x;
  const int wave = tid >> 6;
  const int d = dh * 256 + tid;
  const unsigned int nblk = gridDim.x * gridDim.y * gridDim.z;   // 512

  __shared__ unsigned int sdu[CHUNK][256];   // 32 KB: (dt,u) packed words
  __shared__ float sBC[CHUNK][32];           //  4 KB: B (0..15) | C (16..31)

  const size_t mbase = (size_t)bb * LSEQ + cc * CHUNK;

  // ---- async stage: dtu tile 32x256 u32 (8 calls), BC tile 32x32 f (1) ----
#pragma unroll
  for (int q = 0; q < 8; ++q) {
    int c = q * 256 + tid;   // chunk id; row = c>>6, col4 = (c&63)*4
    load_lds16(dtu + (mbase + (c >> 6)) * DI + dh * 256 + (c & 63) * 4,
               (char*)&sdu[0][0] + (size_t)(q * 256 + wave * 64) * 16);
  }
  load_lds16(dbcBC + (mbase + (tid >> 3)) * 32 + (tid & 7) * 4,
             (char*)&sBC[0][0] + (size_t)(wave * 64) * 16);

  float Ads[16];
  {
    const f32x4* pa = (const f32x4*)(A_log + (size_t)d * DS);
#pragma unroll
    for (int q = 0; q < 4; ++q) {
      f32x4 v = pa[q];
#pragma unroll
      for (int r = 0; r < 4; ++r) Ads[q * 4 + r] = -__expf(v[r]);
    }
  }
  __syncthreads();   // drains vmcnt before LDS reads

  // ---- phase 1: local scan from h=0 ----
  float h[16];
#pragma unroll
  for (int s = 0; s < 16; ++s) h[s] = 0.f;
  float dts = 0.f;
#pragma unroll 4
  for (int tt = 0; tt < CHUNK; ++tt) {
    unsigned int wv = sdu[tt][tid];
    float dt = bf2f((unsigned short)(wv >> 16));
    float u  = bf2f((unsigned short)(wv & 0xffff));
    dts += dt;
    float cdu = dt * u;
    f32x4 B0 = *(const f32x4*)&sBC[tt][0];
    f32x4 B1 = *(const f32x4*)&sBC[tt][4];
    f32x4 B2 = *(const f32x4*)&sBC[tt][8];
    f32x4 B3 = *(const f32x4*)&sBC[tt][12];
#pragma unroll
    for (int r = 0; r < 4; ++r) h[r]      = fmaf(__expf(dt * Ads[r]),      h[r],      cdu * B0[r]);
#pragma unroll
    for (int r = 0; r < 4; ++r) h[4 + r]  = fmaf(__expf(dt * Ads[4 + r]),  h[4 + r],  cdu * B1[r]);
#pragma unroll
    for (int r = 0; r < 4; ++r) h[8 + r]  = fmaf(__expf(dt * Ads[8 + r]),  h[8 + r],  cdu * B2[r]);
#pragma unroll
    for (int r = 0; r < 4; ++r) h[12 + r] = fmaf(__expf(dt * Ads[12 + r]), h[12 + r], cdu * B3[r]);
  }
  const size_t ci = (size_t)(bb * NC + cc) * DI + d;
  {
    f32x4* ph = (f32x4*)(hend + ci * DS);
#pragma unroll
    for (int q = 0; q < 4; ++q) {
      f32x4 v;
#pragma unroll
      for (int r = 0; r < 4; ++r) v[r] = h[q * 4 + r];
      ph[q] = v;
    }
    Ssum[ci] = dts;
  }

  gridbar(bar + 0, nblk);

  // ---- phase 2: serial chunk combine -> hin (on 256 of the 512 blocks) ----
  if (cc < 16) {
    const int dblk = dh * 16 + cc;
    const int di = tid >> 4, s2 = tid & 15;
    const int dd = dblk * 16 + di;
    const float A2 = -__expf(A_log[dd * DS + s2]);
    float hh = 0.f;
#pragma unroll 4
    for (int j = 0; j < NC; ++j) {
      size_t cj = (size_t)(bb * NC + j) * DI + dd;
      hin[cj * DS + s2] = hh;
      hh = fmaf(__expf(A2 * Ssum[cj]), hh, hend[cj * DS + s2]);
    }
  }

  gridbar(bar + 1, nblk);

  // ---- phase 3: re-scan from true h_in, y dot + gate -> yb ----
  {
    const f32x4* ph = (const f32x4*)(hin + ci * DS);
#pragma unroll
    for (int q = 0; q < 4; ++q) {
      f32x4 v = ph[q];
#pragma unroll
      for (int r = 0; r < 4; ++r) h[q * 4 + r] = v[r];
    }
  }
  const float Dsk = D_skip[d];
  const unsigned short* pz = xzb + mbase * 1024 + DI + d;
  unsigned short* py = yb + mbase * DI + d;
#pragma unroll 4
  for (int tt = 0; tt < CHUNK; ++tt) {
    unsigned int wv = sdu[tt][tid];
    float dt = bf2f((unsigned short)(wv >> 16));
    float u  = bf2f((unsigned short)(wv & 0xffff));
    float cdu = dt * u;
    float y = u * Dsk;
    f32x4 B0 = *(const f32x4*)&sBC[tt][0];
    f32x4 B1 = *(const f32x4*)&sBC[tt][4];
    f32x4 B2 = *(const f32x4*)&sBC[tt][8];
    f32x4 B3 = *(const f32x4*)&sBC[tt][12];
    f32x4 C0 = *(const f32x4*)&sBC[tt][16];
    f32x4 C1 = *(const f32x4*)&sBC[tt][20];
    f32x4 C2 = *(const f32x4*)&sBC[tt][24];
    f32x4 C3 = *(const f32x4*)&sBC[tt][28];
#pragma unroll
    for (int r = 0; r < 4; ++r) { h[r]      = fmaf(__expf(dt * Ads[r]),      h[r],      cdu * B0[r]); y = fmaf(h[r],      C0[r], y); }
#pragma unroll
    for (int r = 0; r < 4; ++r) { h[4 + r]  = fmaf(__expf(dt * Ads[4 + r]),  h[4 + r],  cdu * B1[r]); y = fmaf(h[4 + r],  C1[r], y); }
#pragma unroll
    for (int r = 0; r < 4; ++r) { h[8 + r]  = fmaf(__expf(dt * Ads[8 + r]),  h[8 + r],  cdu * B2[r]); y = fmaf(h[8 + r],  C2[r], y); }
#pragma unroll
    for (int r = 0; r < 4; ++r) { h[12 + r] = fmaf(__expf(dt * Ads[12 + r]), h[12 + r], cdu * B3[r]); y = fmaf(h[12 + r], C3[r], y); }
    float z = bf2f(pz[(size_t)tt * 1024]);
    y *= z / (1.f + __expf(-z));
    py[(size_t)tt * DI] = f2bf(y);
  }
}

// ---------------------------------------------------------------------------
extern "C" void kernel_launch(void* const* d_in, const int* in_sizes, int n_in,
                              void* d_out, int out_size, void* d_ws, size_t ws_size,
                              hipStream_t stream) {
  const float* x       = (const float*)d_in[0];
  const float* ln_g    = (const float*)d_in[1];
  const float* ln_b    = (const float*)d_in[2];
  const float* W_in    = (const float*)d_in[3];
  const float* conv_w  = (const float*)d_in[4];
  const float* conv_b  = (const float*)d_in[5];
  const float* W_xproj = (const float*)d_in[6];
  const float* W_dt    = (const float*)d_in[7];
  const float* b_dt    = (const float*)d_in[8];
  const float* A_log   = (const float*)d_in[9];
  const float* D_skip  = (const float*)d_in[10];
  const float* W_out   = (const float*)d_in[11];
  float* out = (float*)d_out;

  // Workspace layout
  float* ws    = (float*)d_ws;
  float* dbcBC = ws;                                    //   262,144 f
  float* hend  = dbcBC + (size_t)MROWS * 32;            // 2,097,152 f
  float* hin   = hend + (size_t)BATCH * NC * DI * DS;   // 2,097,152 f
  float* Ssum  = hin  + (size_t)BATCH * NC * DI * DS;   //   131,072 f
  unsigned int* dtu = (unsigned int*)(Ssum + (size_t)BATCH * NC * DI); // 4,194,304 u32
  unsigned short* xzb  = (unsigned short*)(dtu + (size_t)MROWS * DI); // 8,388,608 us
  unsigned short* yb   = xzb + (size_t)MROWS * 1024;    // 4,194,304 us
  unsigned short* xnb  = yb;   // alias: xnb dead before scan writes yb
  unsigned short* Wib  = yb  + (size_t)MROWS * DI;      // 262,144 us
  unsigned short* Wob  = Wib + (size_t)DIMC * 1024;     // 131,072 us
  unsigned short* Wxpb = Wob + (size_t)DI * DIMC;       //  32,768 us
  unsigned short* Wdtb = Wxpb + (size_t)64 * 512;       //  16,384 us
  unsigned int*   bar  = (unsigned int*)(Wdtb + (size_t)512 * 32);  // 2 u32

  // 0. prologue: weight prep + LayerNorm, one launch
  prologue<<<704, 256, 0, stream>>>(W_in, W_out, W_xproj, W_dt, x, ln_g, ln_b,
                                    Wib, Wob, Wxpb, Wdtb, xnb);

  // 1. xzb = bf16(xn @ W_in)   (8192x1024x256, bf16 MFMA, 128x128 tile)
  gemm_bf16_128<<<dim3(1024 / 128, MROWS / 128), 256, 0, stream>>>(
      xnb, Wib, xzb, MROWS, 1024, DIMC);

  // 2. fused: conv+SiLU (in LDS) ; dbcBC = (B|C) of u @ W_xproj ; dtu pack
  //    (also zeroes scan barrier counters)
  conv_xproj_dt<<<MROWS / 16, 256, 0, stream>>>(xzb, conv_w, conv_b,
                                                Wxpb, Wdtb, b_dt, dbcBC, dtu, bar);

  // 3. fully fused selective scan: 1 launch, 2 grid barriers (bounded spin)
  scan_all<<<dim3(BATCH, 2, NC), 256, 0, stream>>>(
      dtu, dbcBC, xzb, A_log, D_skip, hend, Ssum, hin, bar, yb);

  // 4. out = yb @ W_out (transpose epilogue, +x residual)
  gemm_bf16<<<dim3(DIMC / GTN, MROWS / GTM), 256, 0, stream>>>(
      yb, Wob, out, MROWS, DIMC, DI, 1, x);
}

// Round 7
// 224.902 us; speedup vs baseline: 1.4301x; 1.4301x over previous
//
#include <hip/hip_runtime.h>
#include <hip/hip_bf16.h>
#include <math.h>

// Problem constants
#define DIMC   256      // DIM
#define DI     512      // D_INNER
#define DS     16       // D_STATE
#define DTR    16       // DT_RANK
#define NX     48       // DT_RANK + 2*D_STATE
#define BATCH  8
#define LSEQ   1024     // H*W
#define MROWS  8192     // BATCH*LSEQ
#define CHUNK  32       // scan chunk (32 -> 512 blocks for the d-per-lane scan)
#define NC     (LSEQ / CHUNK)   // 32 chunks

typedef __attribute__((ext_vector_type(8))) short short8;
typedef __attribute__((ext_vector_type(4))) float f32x4;

__device__ __forceinline__ unsigned short f2bf(float v) {
  __hip_bfloat16 h = __float2bfloat16(v);
  return *reinterpret_cast<unsigned short*>(&h);
}
__device__ __forceinline__ float bf2f(unsigned short u) {
  return __int_as_float(((int)u) << 16);
}

// Async global->LDS, 16B per lane. lds base must be wave-uniform; HW writes
// lane i's 16B to ldsbase + i*16 (m97 pattern).
__device__ __forceinline__ void load_lds16(const void* g, void* l) {
  __builtin_amdgcn_global_load_lds(
      (const __attribute__((address_space(1))) unsigned int*)g,
      (__attribute__((address_space(3))) unsigned int*)l, 16, 0, 0);
}

// ---------------------------------------------------------------------------
// Prologue: weight prep + LayerNorm in ONE launch (branch on blockIdx.x).
__global__ __launch_bounds__(256) void prologue(const float* __restrict__ W_in,
                                                const float* __restrict__ W_out,
                                                const float* __restrict__ W_xproj,
                                                const float* __restrict__ W_dt,
                                                const float* __restrict__ x,
                                                const float* __restrict__ gamma,
                                                const float* __restrict__ beta,
                                                unsigned short* __restrict__ Wib,
                                                unsigned short* __restrict__ Wob,
                                                unsigned short* __restrict__ Wxpb,
                                                unsigned short* __restrict__ Wdtb,
                                                unsigned short* __restrict__ xnb) {
  __shared__ float sx[DIMC][67];
  __shared__ float smean[64], srs[64];
  const int blk = blockIdx.x, tid = threadIdx.x;
  if (blk < 384) {
    float (*t)[67] = sx;
    const float* W; unsigned short* Wt; int K, N, bx, by;
    if (blk < 256) { W = W_in;  Wt = Wib; K = DIMC; N = 1024; bx = blk & 31; by = blk >> 5; }
    else           { W = W_out; Wt = Wob; K = DI;   N = DIMC; bx = (blk - 256) & 7; by = (blk - 256) >> 3; }
    int n0 = bx * 32, k0 = by * 32;
    int tx = tid & 31, ty = tid >> 5;
    for (int i = ty; i < 32; i += 8) t[i][tx] = W[(size_t)(k0 + i) * N + n0 + tx];
    __syncthreads();
    for (int i = ty; i < 32; i += 8)
      Wt[(size_t)(n0 + i) * K + k0 + tx] = f2bf(t[tx][i]);
    return;
  }
  if (blk < 512) {
    int idx = (blk - 384) * 256 + tid;   // < 64*512
    int n = idx >> 9, k = idx & 511;
    Wxpb[idx] = (n < NX) ? f2bf(W_xproj[(size_t)k * NX + n]) : (unsigned short)0;
    return;
  }
  if (blk < 576) {
    int idx = (blk - 512) * 256 + tid;   // < 512*32
    int n = idx >> 5, k = idx & 31;
    Wdtb[idx] = (k < DTR) ? f2bf(W_dt[(size_t)k * DI + n]) : (unsigned short)0;
    return;
  }
  // ---- LayerNorm ----
  const int lb = blk - 576;
  const int b = lb >> 4, l0 = (lb & 15) * 64;
  {
    const int cbase = tid >> 2;
    const int lp = (tid & 3) * 16;
#pragma unroll
    for (int cg = 0; cg < 4; ++cg) {
      const int c = cg * 64 + cbase;
      const float* p = x + ((size_t)b * DIMC + c) * LSEQ + l0 + lp;
#pragma unroll
      for (int q = 0; q < 4; ++q) {
        float4 v = *(const float4*)(p + q * 4);
        sx[c][lp + q * 4 + 0] = v.x;
        sx[c][lp + q * 4 + 1] = v.y;
        sx[c][lp + q * 4 + 2] = v.z;
        sx[c][lp + q * 4 + 3] = v.w;
      }
    }
  }
  __syncthreads();
  {
    const int lane = tid & 63, w = tid >> 6;
    const int l = (w << 4) + (lane & 15);
    const int quad = lane >> 4;
    float sum = 0.f, sq = 0.f;
#pragma unroll 8
    for (int cc = 0; cc < 64; ++cc) {
      float v = sx[quad * 64 + cc][l];
      sum += v; sq += v * v;
    }
    sum += __shfl_xor(sum, 16); sq += __shfl_xor(sq, 16);
    sum += __shfl_xor(sum, 32); sq += __shfl_xor(sq, 32);
    if (quad == 0) {
      float mean = sum * (1.f / 256.f);
      float var  = sq * (1.f / 256.f) - mean * mean;
      smean[l] = mean; srs[l] = rsqrtf(var + 1e-5f);
    }
  }
  __syncthreads();
  {
    const float gg = gamma[tid], bb = beta[tid];
    const size_t base = ((size_t)b * LSEQ + l0) * DIMC + tid;
#pragma unroll 4
    for (int ll = 0; ll < 64; ++ll) {
      float v = (sx[tid][ll] - smean[ll]) * srs[ll] * gg + bb;
      xnb[base + (size_t)ll * DIMC] = f2bf(v);
    }
  }
}

// ---------------------------------------------------------------------------
// bf16 MFMA GEMM, m97 structure: 128x128 tile, 4x4 acc/wave, BK=32.
// C(bf16 [M][N]) = A(bf16 [M][K]) * Bt(bf16 [N][K])^T.  (used for gemm1)
__global__ __launch_bounds__(256) void gemm_bf16_128(const unsigned short* __restrict__ A,
                                                     const unsigned short* __restrict__ Bt,
                                                     unsigned short* __restrict__ Cb,
                                                     int M, int N, int K) {
  __shared__ unsigned short As[128][32];
  __shared__ unsigned short Bs[128][32];
  const int tid = threadIdx.x;
  const int lane = tid & 63, wave = tid >> 6;
  const int wm = wave >> 1, wn = wave & 1;
  const int quad = lane >> 4, l16 = lane & 15;
  const int m0 = blockIdx.y * 128, n0 = blockIdx.x * 128;

  f32x4 acc[4][4];
#pragma unroll
  for (int i = 0; i < 4; ++i)
#pragma unroll
    for (int j = 0; j < 4; ++j) acc[i][j] = (f32x4){0.f, 0.f, 0.f, 0.f};

  for (int k0 = 0; k0 < K; k0 += 32) {
    // A tile: 512 chunks of 16B (2/thread); LDS offset = id*16 (linear).
#pragma unroll
    for (int q = 0; q < 2; ++q) {
      int id = q * 256 + tid;
      int row = id >> 2, c = id & 3;
      load_lds16(A + (size_t)(m0 + row) * K + k0 + c * 8,
                 (char*)&As[0][0] + (size_t)(q * 256 + wave * 64) * 16);
    }
    // B tile: 512 chunks (2/thread).
#pragma unroll
    for (int q = 0; q < 2; ++q) {
      int id = q * 256 + tid;
      int row = id >> 2, c = id & 3;
      load_lds16(Bt + (size_t)(n0 + row) * K + k0 + c * 8,
                 (char*)&Bs[0][0] + (size_t)(q * 256 + wave * 64) * 16);
    }
    __syncthreads();   // drains vmcnt before LDS reads
    short8 af[4], bfr[4];
#pragma unroll
    for (int i = 0; i < 4; ++i)
      af[i] = *(const short8*)&As[wm * 64 + i * 16 + l16][quad * 8];
#pragma unroll
    for (int j = 0; j < 4; ++j)
      bfr[j] = *(const short8*)&Bs[wn * 64 + j * 16 + l16][quad * 8];
#pragma unroll
    for (int i = 0; i < 4; ++i)
#pragma unroll
      for (int j = 0; j < 4; ++j)
        acc[i][j] = __builtin_amdgcn_mfma_f32_16x16x32_bf16(af[i], bfr[j], acc[i][j], 0, 0, 0);
    __syncthreads();
  }

#pragma unroll
  for (int i = 0; i < 4; ++i) {
    int rowb = wm * 64 + i * 16 + quad * 4;
#pragma unroll
    for (int j = 0; j < 4; ++j) {
      int n = n0 + wn * 64 + j * 16 + l16;
#pragma unroll
      for (int r = 0; r < 4; ++r)
        Cb[(size_t)(m0 + rowb + r) * N + n] = f2bf(acc[i][j][r]);
    }
  }
}

// ---------------------------------------------------------------------------
// bf16 MFMA GEMM: C = A(bf16 [M][K]) * Bt(bf16 [N][K])^T.  128x64 tile.
// mode 1: f32 out[b*DIMC*LSEQ + n*LSEQ + l] = acc + X  (transpose + residual)
#define GTM 128
#define GTN 64
#define GBK 32
__global__ __launch_bounds__(256) void gemm_bf16(const unsigned short* __restrict__ A,
                                                 const unsigned short* __restrict__ Bt,
                                                 void* __restrict__ Cout,
                                                 int M, int N, int K, int mode,
                                                 const float* __restrict__ X) {
  __shared__ unsigned short As[GTM][GBK];
  __shared__ unsigned short Bs[GTN][GBK];
  const int tid = threadIdx.x;
  const int lane = tid & 63, wave = tid >> 6;
  const int wm = wave >> 1, wn = wave & 1;
  const int quad = lane >> 4, l16 = lane & 15;
  const int m0 = blockIdx.y * GTM, n0 = blockIdx.x * GTN;

  f32x4 acc[4][2];
#pragma unroll
  for (int i = 0; i < 4; ++i)
#pragma unroll
    for (int j = 0; j < 2; ++j) acc[i][j] = (f32x4){0.f, 0.f, 0.f, 0.f};

  for (int k0 = 0; k0 < K; k0 += GBK) {
#pragma unroll
    for (int q = 0; q < 2; ++q) {
      int id = q * 256 + tid;
      int row = id >> 2, c = id & 3;
      load_lds16(A + (size_t)(m0 + row) * K + k0 + c * 8,
                 (char*)&As[0][0] + (size_t)(q * 256 + wave * 64) * 16);
    }
    {
      int row = tid >> 2, c = tid & 3;
      load_lds16(Bt + (size_t)(n0 + row) * K + k0 + c * 8,
                 (char*)&Bs[0][0] + (size_t)(wave * 64) * 16);
    }
    __syncthreads();   // drains vmcnt before LDS reads
    short8 af[4], bfrag[2];
#pragma unroll
    for (int i = 0; i < 4; ++i)
      af[i] = *(const short8*)&As[wm * 64 + i * 16 + l16][quad * 8];
#pragma unroll
    for (int j = 0; j < 2; ++j)
      bfrag[j] = *(const short8*)&Bs[wn * 32 + j * 16 + l16][quad * 8];
#pragma unroll
    for (int i = 0; i < 4; ++i)
#pragma unroll
      for (int j = 0; j < 2; ++j)
        acc[i][j] = __builtin_amdgcn_mfma_f32_16x16x32_bf16(af[i], bfrag[j], acc[i][j], 0, 0, 0);
    __syncthreads();
  }

  if (mode == 2) {
    unsigned short* Cb = (unsigned short*)Cout;
#pragma unroll
    for (int i = 0; i < 4; ++i) {
      int rowb = wm * 64 + i * 16 + quad * 4;
#pragma unroll
      for (int j = 0; j < 2; ++j) {
        int n = n0 + wn * 32 + j * 16 + l16;
#pragma unroll
        for (int r = 0; r < 4; ++r)
          Cb[(size_t)(m0 + rowb + r) * N + n] = f2bf(acc[i][j][r]);
      }
    }
  } else {
    float* C = (float*)Cout;
#pragma unroll
    for (int i = 0; i < 4; ++i) {
      int m = m0 + wm * 64 + i * 16 + quad * 4;
      int b = m >> 10, l = m & 1023;
#pragma unroll
      for (int j = 0; j < 2; ++j) {
        int n = n0 + wn * 32 + j * 16 + l16;
        size_t o = (size_t)b * (DIMC * LSEQ) + (size_t)n * LSEQ + l;
        f32x4 xv = *(const f32x4*)(X + o);
        f32x4 rv = acc[i][j] + xv;
        *(f32x4*)(C + o) = rv;
      }
    }
  }
}

// ---------------------------------------------------------------------------
// Fused conv + SiLU + xproj + dt (MFMA).
// m-tile 16, grid 512 (2 blocks/CU co-resident = 2 waves/SIMD).
// xproj uses TWO independent MFMA accumulator chains (k halves) for 2x ILP.
// Also zeroes the scan last-finisher counters (kernel boundary orders this
// before scan_pass1's atomics).
__global__ __launch_bounds__(256) void conv_xproj_dt(
    const unsigned short* __restrict__ xzb,
    const float* __restrict__ conv_w,
    const float* __restrict__ conv_b,
    const unsigned short* __restrict__ Wxpb,
    const unsigned short* __restrict__ Wdtb,
    const float* __restrict__ b_dt,
    float* __restrict__ dbcBC,
    unsigned int* __restrict__ dtu,
    unsigned int* __restrict__ cnt) {
  __shared__ unsigned short sxz[19][512];       // 16 rows + 3 halo
  __shared__ unsigned short su[16][512 + 8];
  __shared__ unsigned short sdbc[16][40];
  const int m0 = blockIdx.x * 16;
  const int l0 = m0 & 1023;
  const int tid = threadIdx.x, lane = tid & 63, w = tid >> 6;
  const int quad = lane >> 4, l16 = lane & 15;

  if (blockIdx.x == 0 && tid < 16) cnt[tid] = 0u;

  // Stage the xz u-half tile with halo: 19*64 = 1216 chunks of 8 bf16.
#pragma unroll
  for (int q = 0; q < 5; ++q) {
    int id = q * 256 + tid;
    if (id < 19 * 64) {
      int rr = id >> 6, c8 = id & 63;
      uint4 v; v.x = 0u; v.y = 0u; v.z = 0u; v.w = 0u;
      if (l0 - 3 + rr >= 0)
        v = *(const uint4*)(xzb + (size_t)(m0 - 3 + rr) * 1024 + c8 * 8);
      *(uint4*)&sxz[rr][c8 * 8] = v;
    }
  }
  __syncthreads();

  // conv(k=4) + bias + SiLU -> su (32 outputs/thread, coalesced in c).
#pragma unroll 4
  for (int q = 0; q < 32; ++q) {
    int idx = q * 256 + tid;
    int r = idx >> 9, c = idx & 511;
    float4 wv = *(const float4*)(conv_w + c * 4);
    float acc = conv_b[c];
    acc = fmaf(bf2f(sxz[r + 0][c]), wv.x, acc);
    acc = fmaf(bf2f(sxz[r + 1][c]), wv.y, acc);
    acc = fmaf(bf2f(sxz[r + 2][c]), wv.z, acc);
    acc = fmaf(bf2f(sxz[r + 3][c]), wv.w, acc);
    float u = acc / (1.f + __expf(-acc));
    su[r][c] = f2bf(u);
  }
  __syncthreads();

  // xproj MFMA: A-frags from su, B-frags from global (L2-hot).
  // Two independent accumulator chains over k halves -> 2x MFMA ILP.
  f32x4 acc0 = (f32x4){0.f, 0.f, 0.f, 0.f};
  f32x4 acc1 = (f32x4){0.f, 0.f, 0.f, 0.f};
#pragma unroll 4
  for (int k0 = 0; k0 < 256; k0 += 32) {
    short8 afA = *(const short8*)&su[l16][k0 + quad * 8];
    short8 bfA = *(const short8*)(Wxpb + (size_t)(w * 16 + l16) * 512 + k0 + quad * 8);
    acc0 = __builtin_amdgcn_mfma_f32_16x16x32_bf16(afA, bfA, acc0, 0, 0, 0);
    short8 afB = *(const short8*)&su[l16][256 + k0 + quad * 8];
    short8 bfB = *(const short8*)(Wxpb + (size_t)(w * 16 + l16) * 512 + 256 + k0 + quad * 8);
    acc1 = __builtin_amdgcn_mfma_f32_16x16x32_bf16(afB, bfB, acc1, 0, 0, 0);
  }
  f32x4 acc = acc0 + acc1;
  // Persist only B (n=16..31) and C (n=32..47) columns.
  if (w == 1 || w == 2) {
#pragma unroll
    for (int r = 0; r < 4; ++r)
      dbcBC[(size_t)(m0 + quad * 4 + r) * 32 + (w - 1) * 16 + l16] = acc[r];
  }
  if (w < 2) {
#pragma unroll
    for (int r = 0; r < 4; ++r)
      sdbc[quad * 4 + r][w * 16 + l16] = f2bf(acc[r]);
  }
  __syncthreads();

  // dt MFMA + softplus + dtu pack (u pulled from su).
  short8 af0 = *(const short8*)&sdbc[l16][quad * 8];
#pragma unroll
  for (int jn = 0; jn < 8; ++jn) {
    const int n0 = w * 128 + jn * 16;
    short8 bf = *(const short8*)(Wdtb + (size_t)(n0 + l16) * 32 + quad * 8);
    f32x4 a0 = (f32x4){0.f, 0.f, 0.f, 0.f};
    a0 = __builtin_amdgcn_mfma_f32_16x16x32_bf16(af0, bf, a0, 0, 0, 0);
    const float bd = b_dt[n0 + l16];
#pragma unroll
    for (int r = 0; r < 4; ++r) {
      int lr0 = quad * 4 + r;
      float v = a0[r] + bd;
      float sp = (v > 20.f) ? v : log1pf(__expf(v));
      unsigned int u0 = (unsigned int)su[lr0][n0 + l16];
      dtu[(size_t)(m0 + lr0) * DI + n0 + l16] = u0 | ((unsigned int)f2bf(sp) << 16);
    }
  }
}

// ---------------------------------------------------------------------------
// Chunked selective scan, d-per-lane layout.
//
// Pass 1 + merged combine (last-finisher): local scan from h=0 -> hend, Ssum.
// Each block then signals cnt[bb*2+dh] with an ACQ_REL fetch_add (its stores
// are vmcnt-drained by the preceding __syncthreads, and the release orders
// them to memory). The block observing old==NC-1 is the LAST for its
// (bb,dh) slice: it acquires (threadfence) and runs the serial chunk-combine
// -> hin for all 256 d of the slice. No spin-waits, no co-residency
// assumptions; a broken fence shows as absmax failure, never a hang.
__global__ __launch_bounds__(256) void scan_pass1(const unsigned int* __restrict__ dtu,
                                                  const float* __restrict__ dbcBC,
                                                  const float* __restrict__ A_log,
                                                  float* __restrict__ hend,
                                                  float* __restrict__ Ssum,
                                                  float* __restrict__ hin,
                                                  unsigned int* __restrict__ cnt) {
  const int bb = blockIdx.x, dh = blockIdx.y, cc = blockIdx.z;
  const int tid = threadIdx.x;
  const int d = dh * 256 + tid;

  __shared__ float sB[CHUNK][16];
  __shared__ int sFin;
  const size_t mbase = (size_t)bb * LSEQ + cc * CHUNK;
#pragma unroll
  for (int q = 0; q < 2; ++q) {
    int lin = q * 256 + tid;
    int tt = lin >> 4, ss = lin & 15;
    sB[tt][ss] = dbcBC[(mbase + tt) * 32 + ss];
  }

  float Ads[16];
  {
    const f32x4* pa = (const f32x4*)(A_log + (size_t)d * DS);
#pragma unroll
    for (int q = 0; q < 4; ++q) {
      f32x4 v = pa[q];
#pragma unroll
      for (int r = 0; r < 4; ++r) Ads[q * 4 + r] = -__expf(v[r]);
    }
  }
  __syncthreads();

  float h[16];
#pragma unroll
  for (int s = 0; s < 16; ++s) h[s] = 0.f;
  float dts = 0.f;
  const unsigned int* pdu = dtu + mbase * DI + d;
#pragma unroll 4
  for (int tt = 0; tt < CHUNK; ++tt) {
    unsigned int wv = pdu[(size_t)tt * DI];
    float dt = bf2f((unsigned short)(wv >> 16));
    float u  = bf2f((unsigned short)(wv & 0xffff));
    dts += dt;
    float c = dt * u;
#pragma unroll
    for (int s = 0; s < 16; ++s)
      h[s] = fmaf(__expf(dt * Ads[s]), h[s], c * sB[tt][s]);
  }
  const size_t ci = (size_t)(bb * NC + cc) * DI + d;
  {
    f32x4* ph = (f32x4*)(hend + ci * DS);
#pragma unroll
    for (int q = 0; q < 4; ++q) {
      f32x4 v;
#pragma unroll
      for (int r = 0; r < 4; ++r) v[r] = h[q * 4 + r];
      ph[q] = v;
    }
    Ssum[ci] = dts;
  }

  // ---- signal; last finisher runs the combine for this (bb,dh) slice ----
  __syncthreads();   // all stores above are vmcnt-drained at this barrier
  if (tid == 0) {
    unsigned int old = __hip_atomic_fetch_add(&cnt[bb * 2 + dh], 1u,
                                              __ATOMIC_ACQ_REL,
                                              __HIP_MEMORY_SCOPE_AGENT);
    sFin = (old == NC - 1) ? 1 : 0;
  }
  __syncthreads();
  if (sFin) {
    __threadfence();   // acquire: see all other blocks' hend/Ssum
    float hh[16];
#pragma unroll
    for (int s = 0; s < 16; ++s) hh[s] = 0.f;
    for (int j = 0; j < NC; ++j) {
      const size_t cj = (size_t)(bb * NC + j) * DI + d;
      f32x4* po = (f32x4*)(hin + cj * DS);
#pragma unroll
      for (int q = 0; q < 4; ++q) {
        f32x4 v;
#pragma unroll
        for (int r = 0; r < 4; ++r) v[r] = hh[q * 4 + r];
        po[q] = v;
      }
      const float Sj = Ssum[cj];
      const f32x4* pe = (const f32x4*)(hend + cj * DS);
#pragma unroll
      for (int q = 0; q < 4; ++q) {
        f32x4 e = pe[q];
#pragma unroll
        for (int r = 0; r < 4; ++r)
          hh[q * 4 + r] = fmaf(__expf(Ads[q * 4 + r] * Sj), hh[q * 4 + r], e[r]);
      }
    }
  }
}

// Pass 3: re-run each chunk from true h_in, y as in-register dot, fused
// gate epilogue -> yb (bf16). Grid (BATCH, 2, NC).
__global__ __launch_bounds__(256) void scan_pass3(const unsigned int* __restrict__ dtu,
                                                  const float* __restrict__ dbcBC,
                                                  const unsigned short* __restrict__ xzb,
                                                  const float* __restrict__ A_log,
                                                  const float* __restrict__ D_skip,
                                                  const float* __restrict__ hin,
                                                  unsigned short* __restrict__ yb) {
  const int bb = blockIdx.x, dh = blockIdx.y, cc = blockIdx.z;
  const int tid = threadIdx.x;
  const int d = dh * 256 + tid;

  __shared__ float sB[CHUNK][16];
  __shared__ float sC[CHUNK][16];
  const size_t mbase = (size_t)bb * LSEQ + cc * CHUNK;
#pragma unroll
  for (int q = 0; q < 2; ++q) {
    int lin = q * 256 + tid;
    int tt = lin >> 4, ss = lin & 15;
    sB[tt][ss] = dbcBC[(mbase + tt) * 32 + ss];
    sC[tt][ss] = dbcBC[(mbase + tt) * 32 + 16 + ss];
  }

  float Ads[16];
  {
    const f32x4* pa = (const f32x4*)(A_log + (size_t)d * DS);
#pragma unroll
    for (int q = 0; q < 4; ++q) {
      f32x4 v = pa[q];
#pragma unroll
      for (int r = 0; r < 4; ++r) Ads[q * 4 + r] = -__expf(v[r]);
    }
  }

  float h[16];
  {
    const f32x4* ph = (const f32x4*)(hin + ((size_t)(bb * NC + cc) * DI + d) * DS);
#pragma unroll
    for (int q = 0; q < 4; ++q) {
      f32x4 v = ph[q];
#pragma unroll
      for (int r = 0; r < 4; ++r) h[q * 4 + r] = v[r];
    }
  }
  __syncthreads();

  const float Dsk = D_skip[d];
  const unsigned int* pdu = dtu + mbase * DI + d;
  const unsigned short* pz = xzb + mbase * 1024 + DI + d;
  unsigned short* py = yb + mbase * DI + d;
#pragma unroll 4
  for (int tt = 0; tt < CHUNK; ++tt) {
    unsigned int wv = pdu[(size_t)tt * DI];
    float dt = bf2f((unsigned short)(wv >> 16));
    float u  = bf2f((unsigned short)(wv & 0xffff));
    float c = dt * u;
    float y = u * Dsk;
#pragma unroll
    for (int s = 0; s < 16; ++s) {
      h[s] = fmaf(__expf(dt * Ads[s]), h[s], c * sB[tt][s]);
      y = fmaf(h[s], sC[tt][s], y);
    }
    float z = bf2f(pz[(size_t)tt * 1024]);
    y *= z / (1.f + __expf(-z));
    py[(size_t)tt * DI] = f2bf(y);
  }
}

// ---------------------------------------------------------------------------
extern "C" void kernel_launch(void* const* d_in, const int* in_sizes, int n_in,
                              void* d_out, int out_size, void* d_ws, size_t ws_size,
                              hipStream_t stream) {
  const float* x       = (const float*)d_in[0];
  const float* ln_g    = (const float*)d_in[1];
  const float* ln_b    = (const float*)d_in[2];
  const float* W_in    = (const float*)d_in[3];
  const float* conv_w  = (const float*)d_in[4];
  const float* conv_b  = (const float*)d_in[5];
  const float* W_xproj = (const float*)d_in[6];
  const float* W_dt    = (const float*)d_in[7];
  const float* b_dt    = (const float*)d_in[8];
  const float* A_log   = (const float*)d_in[9];
  const float* D_skip  = (const float*)d_in[10];
  const float* W_out   = (const float*)d_in[11];
  float* out = (float*)d_out;

  // Workspace layout
  float* ws    = (float*)d_ws;
  float* dbcBC = ws;                                    //   262,144 f
  float* hend  = dbcBC + (size_t)MROWS * 32;            // 2,097,152 f
  float* hin   = hend + (size_t)BATCH * NC * DI * DS;   // 2,097,152 f
  float* Ssum  = hin  + (size_t)BATCH * NC * DI * DS;   //   131,072 f
  unsigned int* dtu = (unsigned int*)(Ssum + (size_t)BATCH * NC * DI); // 4,194,304 u32
  unsigned short* xzb  = (unsigned short*)(dtu + (size_t)MROWS * DI); // 8,388,608 us
  unsigned short* yb   = xzb + (size_t)MROWS * 1024;    // 4,194,304 us
  unsigned short* xnb  = yb;   // alias: xnb dead before pass3 writes yb
  unsigned short* Wib  = yb  + (size_t)MROWS * DI;      // 262,144 us
  unsigned short* Wob  = Wib + (size_t)DIMC * 1024;     // 131,072 us
  unsigned short* Wxpb = Wob + (size_t)DI * DIMC;       //  32,768 us
  unsigned short* Wdtb = Wxpb + (size_t)64 * 512;       //  16,384 us
  unsigned int*   cnt  = (unsigned int*)(Wdtb + (size_t)512 * 32);  // 16 u32

  // 0. prologue: weight prep + LayerNorm, one launch
  prologue<<<704, 256, 0, stream>>>(W_in, W_out, W_xproj, W_dt, x, ln_g, ln_b,
                                    Wib, Wob, Wxpb, Wdtb, xnb);

  // 1. xzb = bf16(xn @ W_in)   (8192x1024x256, bf16 MFMA, 128x128 tile)
  gemm_bf16_128<<<dim3(1024 / 128, MROWS / 128), 256, 0, stream>>>(
      xnb, Wib, xzb, MROWS, 1024, DIMC);

  // 2. fused: conv+SiLU (in LDS) ; dbcBC = (B|C) of u @ W_xproj ; dtu pack
  //    (also zeroes the last-finisher counters)
  conv_xproj_dt<<<MROWS / 16, 256, 0, stream>>>(xzb, conv_w, conv_b,
                                                Wxpb, Wdtb, b_dt, dbcBC, dtu, cnt);

  // 3. chunked selective scan: pass1 (+merged last-finisher combine), pass3
  dim3 gp13(BATCH, 2, NC);
  scan_pass1<<<gp13, 256, 0, stream>>>(dtu, dbcBC, A_log, hend, Ssum, hin, cnt);
  scan_pass3<<<gp13, 256, 0, stream>>>(dtu, dbcBC, xzb, A_log, D_skip, hin, yb);

  // 4. out = yb @ W_out (transpose epilogue, +x residual)
  gemm_bf16<<<dim3(DIMC / GTN, MROWS / GTM), 256, 0, stream>>>(
      yb, Wob, out, MROWS, DIMC, DI, 1, x);
}

// Round 8
// 182.297 us; speedup vs baseline: 1.7643x; 1.2337x over previous
//
#include <hip/hip_runtime.h>
#include <hip/hip_bf16.h>
#include <math.h>

// Problem constants
#define DIMC   256      // DIM
#define DI     512      // D_INNER
#define DS     16       // D_STATE
#define DTR    16       // DT_RANK
#define NX     48       // DT_RANK + 2*D_STATE
#define BATCH  8
#define LSEQ   1024     // H*W
#define MROWS  8192     // BATCH*LSEQ
#define CHUNK  64
#define NC     (LSEQ / CHUNK)   // 16 chunks

typedef __attribute__((ext_vector_type(8))) short short8;
typedef __attribute__((ext_vector_type(4))) float f32x4;

__device__ __forceinline__ unsigned short f2bf(float v) {
  __hip_bfloat16 h = __float2bfloat16(v);
  return *reinterpret_cast<unsigned short*>(&h);
}
__device__ __forceinline__ float bf2f(unsigned short u) {
  return __int_as_float(((int)u) << 16);
}

// Async global->LDS, 16B per lane. lds base must be wave-uniform; HW writes
// lane i's 16B to ldsbase + i*16 (m97 pattern).
__device__ __forceinline__ void load_lds16(const void* g, void* l) {
  __builtin_amdgcn_global_load_lds(
      (const __attribute__((address_space(1))) unsigned int*)g,
      (__attribute__((address_space(3))) unsigned int*)l, 16, 0, 0);
}

// Sum across the 16-lane group using DPP only (zero DS ops).
__device__ __forceinline__ float dpp_sum16(float v) {
  float t;
  t = __int_as_float(__builtin_amdgcn_mov_dpp(__float_as_int(v), 0xB1,  0xF, 0xF, true)); v += t; // ^1
  t = __int_as_float(__builtin_amdgcn_mov_dpp(__float_as_int(v), 0x4E,  0xF, 0xF, true)); v += t; // ^2
  t = __int_as_float(__builtin_amdgcn_mov_dpp(__float_as_int(v), 0x141, 0xF, 0xF, true)); v += t; // ^7 (row_half_mirror)
  t = __int_as_float(__builtin_amdgcn_mov_dpp(__float_as_int(v), 0x140, 0xF, 0xF, true)); v += t; // ^15 (row_mirror)
  return v;
}

// ---------------------------------------------------------------------------
// Prologue: weight prep + LayerNorm in ONE launch (branch on blockIdx.x).
__global__ __launch_bounds__(256) void prologue(const float* __restrict__ W_in,
                                                const float* __restrict__ W_out,
                                                const float* __restrict__ W_xproj,
                                                const float* __restrict__ W_dt,
                                                const float* __restrict__ x,
                                                const float* __restrict__ gamma,
                                                const float* __restrict__ beta,
                                                unsigned short* __restrict__ Wib,
                                                unsigned short* __restrict__ Wob,
                                                unsigned short* __restrict__ Wxpb,
                                                unsigned short* __restrict__ Wdtb,
                                                unsigned short* __restrict__ xnb) {
  __shared__ float sx[DIMC][67];
  __shared__ float smean[64], srs[64];
  const int blk = blockIdx.x, tid = threadIdx.x;
  if (blk < 384) {
    float (*t)[67] = sx;
    const float* W; unsigned short* Wt; int K, N, bx, by;
    if (blk < 256) { W = W_in;  Wt = Wib; K = DIMC; N = 1024; bx = blk & 31; by = blk >> 5; }
    else           { W = W_out; Wt = Wob; K = DI;   N = DIMC; bx = (blk - 256) & 7; by = (blk - 256) >> 3; }
    int n0 = bx * 32, k0 = by * 32;
    int tx = tid & 31, ty = tid >> 5;
    for (int i = ty; i < 32; i += 8) t[i][tx] = W[(size_t)(k0 + i) * N + n0 + tx];
    __syncthreads();
    for (int i = ty; i < 32; i += 8)
      Wt[(size_t)(n0 + i) * K + k0 + tx] = f2bf(t[tx][i]);
    return;
  }
  if (blk < 512) {
    int idx = (blk - 384) * 256 + tid;   // < 64*512
    int n = idx >> 9, k = idx & 511;
    Wxpb[idx] = (n < NX) ? f2bf(W_xproj[(size_t)k * NX + n]) : (unsigned short)0;
    return;
  }
  if (blk < 576) {
    int idx = (blk - 512) * 256 + tid;   // < 512*32
    int n = idx >> 5, k = idx & 31;
    Wdtb[idx] = (k < DTR) ? f2bf(W_dt[(size_t)k * DI + n]) : (unsigned short)0;
    return;
  }
  // ---- LayerNorm ----
  const int lb = blk - 576;
  const int b = lb >> 4, l0 = (lb & 15) * 64;
  {
    const int cbase = tid >> 2;
    const int lp = (tid & 3) * 16;
#pragma unroll
    for (int cg = 0; cg < 4; ++cg) {
      const int c = cg * 64 + cbase;
      const float* p = x + ((size_t)b * DIMC + c) * LSEQ + l0 + lp;
#pragma unroll
      for (int q = 0; q < 4; ++q) {
        float4 v = *(const float4*)(p + q * 4);
        sx[c][lp + q * 4 + 0] = v.x;
        sx[c][lp + q * 4 + 1] = v.y;
        sx[c][lp + q * 4 + 2] = v.z;
        sx[c][lp + q * 4 + 3] = v.w;
      }
    }
  }
  __syncthreads();
  {
    const int lane = tid & 63, w = tid >> 6;
    const int l = (w << 4) + (lane & 15);
    const int quad = lane >> 4;
    float sum = 0.f, sq = 0.f;
#pragma unroll 8
    for (int cc = 0; cc < 64; ++cc) {
      float v = sx[quad * 64 + cc][l];
      sum += v; sq += v * v;
    }
    sum += __shfl_xor(sum, 16); sq += __shfl_xor(sq, 16);
    sum += __shfl_xor(sum, 32); sq += __shfl_xor(sq, 32);
    if (quad == 0) {
      float mean = sum * (1.f / 256.f);
      float var  = sq * (1.f / 256.f) - mean * mean;
      smean[l] = mean; srs[l] = rsqrtf(var + 1e-5f);
    }
  }
  __syncthreads();
  {
    const float gg = gamma[tid], bb = beta[tid];
    const size_t base = ((size_t)b * LSEQ + l0) * DIMC + tid;
#pragma unroll 4
    for (int ll = 0; ll < 64; ++ll) {
      float v = (sx[tid][ll] - smean[ll]) * srs[ll] * gg + bb;
      xnb[base + (size_t)ll * DIMC] = f2bf(v);
    }
  }
}

// ---------------------------------------------------------------------------
// bf16 MFMA GEMM, m97 structure: 128x128 tile, 4x4 acc/wave, BK=32.
// C(bf16 [M][N]) = A(bf16 [M][K]) * Bt(bf16 [N][K])^T.  (used for gemm1)
__global__ __launch_bounds__(256) void gemm_bf16_128(const unsigned short* __restrict__ A,
                                                     const unsigned short* __restrict__ Bt,
                                                     unsigned short* __restrict__ Cb,
                                                     int M, int N, int K) {
  __shared__ unsigned short As[128][32];
  __shared__ unsigned short Bs[128][32];
  const int tid = threadIdx.x;
  const int lane = tid & 63, wave = tid >> 6;
  const int wm = wave >> 1, wn = wave & 1;
  const int quad = lane >> 4, l16 = lane & 15;
  const int m0 = blockIdx.y * 128, n0 = blockIdx.x * 128;

  f32x4 acc[4][4];
#pragma unroll
  for (int i = 0; i < 4; ++i)
#pragma unroll
    for (int j = 0; j < 4; ++j) acc[i][j] = (f32x4){0.f, 0.f, 0.f, 0.f};

  for (int k0 = 0; k0 < K; k0 += 32) {
    // A tile: 512 chunks of 16B (2/thread); LDS offset = id*16 (linear).
#pragma unroll
    for (int q = 0; q < 2; ++q) {
      int id = q * 256 + tid;
      int row = id >> 2, c = id & 3;
      load_lds16(A + (size_t)(m0 + row) * K + k0 + c * 8,
                 (char*)&As[0][0] + (size_t)(q * 256 + wave * 64) * 16);
    }
    // B tile: 512 chunks (2/thread).
#pragma unroll
    for (int q = 0; q < 2; ++q) {
      int id = q * 256 + tid;
      int row = id >> 2, c = id & 3;
      load_lds16(Bt + (size_t)(n0 + row) * K + k0 + c * 8,
                 (char*)&Bs[0][0] + (size_t)(q * 256 + wave * 64) * 16);
    }
    __syncthreads();   // drains vmcnt before LDS reads
    short8 af[4], bfr[4];
#pragma unroll
    for (int i = 0; i < 4; ++i)
      af[i] = *(const short8*)&As[wm * 64 + i * 16 + l16][quad * 8];
#pragma unroll
    for (int j = 0; j < 4; ++j)
      bfr[j] = *(const short8*)&Bs[wn * 64 + j * 16 + l16][quad * 8];
#pragma unroll
    for (int i = 0; i < 4; ++i)
#pragma unroll
      for (int j = 0; j < 4; ++j)
        acc[i][j] = __builtin_amdgcn_mfma_f32_16x16x32_bf16(af[i], bfr[j], acc[i][j], 0, 0, 0);
    __syncthreads();
  }

#pragma unroll
  for (int i = 0; i < 4; ++i) {
    int rowb = wm * 64 + i * 16 + quad * 4;
#pragma unroll
    for (int j = 0; j < 4; ++j) {
      int n = n0 + wn * 64 + j * 16 + l16;
#pragma unroll
      for (int r = 0; r < 4; ++r)
        Cb[(size_t)(m0 + rowb + r) * N + n] = f2bf(acc[i][j][r]);
    }
  }
}

// ---------------------------------------------------------------------------
// bf16 MFMA GEMM, 64x64 tile, BK=64, fused transpose+residual epilogue.
// Used for gemm2 (M=8192, N=256, K=512): grid (N/64, M/64) = 512 blocks
// = 2 blocks/CU (vs 1 for the old 128x64 tile) -> 2x occupancy.
// K-accumulation order identical to BK=32 (kk ascending) -> bit-identical.
// out[b*DIMC*LSEQ + n*LSEQ + l] = acc + X.
__global__ __launch_bounds__(256) void gemm_bf16_64(const unsigned short* __restrict__ A,
                                                    const unsigned short* __restrict__ Bt,
                                                    float* __restrict__ C,
                                                    int M, int N, int K,
                                                    const float* __restrict__ X) {
  __shared__ unsigned short As[64][64];
  __shared__ unsigned short Bs[64][64];
  const int tid = threadIdx.x;
  const int lane = tid & 63, wave = tid >> 6;
  const int wm = wave >> 1, wn = wave & 1;
  const int quad = lane >> 4, l16 = lane & 15;
  const int m0 = blockIdx.y * 64, n0 = blockIdx.x * 64;

  f32x4 acc[2][2];
#pragma unroll
  for (int i = 0; i < 2; ++i)
#pragma unroll
    for (int j = 0; j < 2; ++j) acc[i][j] = (f32x4){0.f, 0.f, 0.f, 0.f};

  for (int k0 = 0; k0 < K; k0 += 64) {
    // A tile 64x64: 512 chunks of 16B (2/thread); row = id>>3, c8 = id&7.
#pragma unroll
    for (int q = 0; q < 2; ++q) {
      int id = q * 256 + tid;
      int row = id >> 3, c = id & 7;
      load_lds16(A + (size_t)(m0 + row) * K + k0 + c * 8,
                 (char*)&As[0][0] + (size_t)(q * 256 + wave * 64) * 16);
    }
#pragma unroll
    for (int q = 0; q < 2; ++q) {
      int id = q * 256 + tid;
      int row = id >> 3, c = id & 7;
      load_lds16(Bt + (size_t)(n0 + row) * K + k0 + c * 8,
                 (char*)&Bs[0][0] + (size_t)(q * 256 + wave * 64) * 16);
    }
    __syncthreads();   // drains vmcnt before LDS reads
#pragma unroll
    for (int kk = 0; kk < 64; kk += 32) {
      short8 af[2], bfr[2];
#pragma unroll
      for (int i = 0; i < 2; ++i)
        af[i] = *(const short8*)&As[wm * 32 + i * 16 + l16][kk + quad * 8];
#pragma unroll
      for (int j = 0; j < 2; ++j)
        bfr[j] = *(const short8*)&Bs[wn * 32 + j * 16 + l16][kk + quad * 8];
#pragma unroll
      for (int i = 0; i < 2; ++i)
#pragma unroll
        for (int j = 0; j < 2; ++j)
          acc[i][j] = __builtin_amdgcn_mfma_f32_16x16x32_bf16(af[i], bfr[j], acc[i][j], 0, 0, 0);
    }
    __syncthreads();
  }

#pragma unroll
  for (int i = 0; i < 2; ++i) {
    int m = m0 + wm * 32 + i * 16 + quad * 4;
    int b = m >> 10, l = m & 1023;
#pragma unroll
    for (int j = 0; j < 2; ++j) {
      int n = n0 + wn * 32 + j * 16 + l16;
      size_t o = (size_t)b * (DIMC * LSEQ) + (size_t)n * LSEQ + l;
      f32x4 xv = *(const f32x4*)(X + o);
      f32x4 rv = acc[i][j] + xv;
      *(f32x4*)(C + o) = rv;
    }
  }
}

// ---------------------------------------------------------------------------
// Fused conv + SiLU + xproj + dt (MFMA).
// m-tile 16, grid 512 (2 blocks/CU co-resident = 2 waves/SIMD).
// xproj uses TWO independent MFMA accumulator chains (k halves) for 2x ILP.
__global__ __launch_bounds__(256) void conv_xproj_dt(
    const unsigned short* __restrict__ xzb,
    const float* __restrict__ conv_w,
    const float* __restrict__ conv_b,
    const unsigned short* __restrict__ Wxpb,
    const unsigned short* __restrict__ Wdtb,
    const float* __restrict__ b_dt,
    float* __restrict__ dbcBC,
    unsigned int* __restrict__ dtu) {
  __shared__ unsigned short sxz[19][512];       // 16 rows + 3 halo
  __shared__ unsigned short su[16][512 + 8];
  __shared__ unsigned short sdbc[16][40];
  const int m0 = blockIdx.x * 16;
  const int l0 = m0 & 1023;
  const int tid = threadIdx.x, lane = tid & 63, w = tid >> 6;
  const int quad = lane >> 4, l16 = lane & 15;

  // Stage the xz u-half tile with halo: 19*64 = 1216 chunks of 8 bf16.
#pragma unroll
  for (int q = 0; q < 5; ++q) {
    int id = q * 256 + tid;
    if (id < 19 * 64) {
      int rr = id >> 6, c8 = id & 63;
      uint4 v; v.x = 0u; v.y = 0u; v.z = 0u; v.w = 0u;
      if (l0 - 3 + rr >= 0)
        v = *(const uint4*)(xzb + (size_t)(m0 - 3 + rr) * 1024 + c8 * 8);
      *(uint4*)&sxz[rr][c8 * 8] = v;
    }
  }
  __syncthreads();

  // conv(k=4) + bias + SiLU -> su (32 outputs/thread, coalesced in c).
#pragma unroll 4
  for (int q = 0; q < 32; ++q) {
    int idx = q * 256 + tid;
    int r = idx >> 9, c = idx & 511;
    float4 wv = *(const float4*)(conv_w + c * 4);
    float acc = conv_b[c];
    acc = fmaf(bf2f(sxz[r + 0][c]), wv.x, acc);
    acc = fmaf(bf2f(sxz[r + 1][c]), wv.y, acc);
    acc = fmaf(bf2f(sxz[r + 2][c]), wv.z, acc);
    acc = fmaf(bf2f(sxz[r + 3][c]), wv.w, acc);
    float u = acc / (1.f + __expf(-acc));
    su[r][c] = f2bf(u);
  }
  __syncthreads();

  // xproj MFMA: A-frags from su, B-frags from global (L2-hot).
  // Two independent accumulator chains over k halves -> 2x MFMA ILP.
  f32x4 acc0 = (f32x4){0.f, 0.f, 0.f, 0.f};
  f32x4 acc1 = (f32x4){0.f, 0.f, 0.f, 0.f};
#pragma unroll 4
  for (int k0 = 0; k0 < 256; k0 += 32) {
    short8 afA = *(const short8*)&su[l16][k0 + quad * 8];
    short8 bfA = *(const short8*)(Wxpb + (size_t)(w * 16 + l16) * 512 + k0 + quad * 8);
    acc0 = __builtin_amdgcn_mfma_f32_16x16x32_bf16(afA, bfA, acc0, 0, 0, 0);
    short8 afB = *(const short8*)&su[l16][256 + k0 + quad * 8];
    short8 bfB = *(const short8*)(Wxpb + (size_t)(w * 16 + l16) * 512 + 256 + k0 + quad * 8);
    acc1 = __builtin_amdgcn_mfma_f32_16x16x32_bf16(afB, bfB, acc1, 0, 0, 0);
  }
  f32x4 acc = acc0 + acc1;
  // Persist only B (n=16..31) and C (n=32..47) columns.
  if (w == 1 || w == 2) {
#pragma unroll
    for (int r = 0; r < 4; ++r)
      dbcBC[(size_t)(m0 + quad * 4 + r) * 32 + (w - 1) * 16 + l16] = acc[r];
  }
  if (w < 2) {
#pragma unroll
    for (int r = 0; r < 4; ++r)
      sdbc[quad * 4 + r][w * 16 + l16] = f2bf(acc[r]);
  }
  __syncthreads();

  // dt MFMA + softplus + dtu pack (u pulled from su).
  short8 af0 = *(const short8*)&sdbc[l16][quad * 8];
#pragma unroll
  for (int jn = 0; jn < 8; ++jn) {
    const int n0 = w * 128 + jn * 16;
    short8 bf = *(const short8*)(Wdtb + (size_t)(n0 + l16) * 32 + quad * 8);
    f32x4 a0 = (f32x4){0.f, 0.f, 0.f, 0.f};
    a0 = __builtin_amdgcn_mfma_f32_16x16x32_bf16(af0, bf, a0, 0, 0, 0);
    const float bd = b_dt[n0 + l16];
#pragma unroll
    for (int r = 0; r < 4; ++r) {
      int lr0 = quad * 4 + r;
      float v = a0[r] + bd;
      float sp = (v > 20.f) ? v : log1pf(__expf(v));
      unsigned int u0 = (unsigned int)su[lr0][n0 + l16];
      dtu[(size_t)(m0 + lr0) * DI + n0 + l16] = u0 | ((unsigned int)f2bf(sp) << 16);
    }
  }
}

// ---------------------------------------------------------------------------
// Chunked selective scan, (d,s) LDS-staged layout.
// Pass 1: local scan from h=0 -> hend, sum dt. Grid (BATCH, 32, NC).
__global__ __launch_bounds__(256) void scan_pass1(const unsigned int* __restrict__ dtu,
                                                  const float* __restrict__ dbcBC,
                                                  const float* __restrict__ A_log,
                                                  float* __restrict__ hend,
                                                  float* __restrict__ Ssum) {
  const int bb = blockIdx.x, dblk = blockIdx.y, cc = blockIdx.z;
  const int tid = threadIdx.x;
  const int di = tid >> 4, s = tid & 15;
  const int d = dblk * 16 + di;
  const float Ads = -__expf(A_log[d * DS + s]);

  __shared__ float2 sdu[CHUNK][18];   // (dt, u); pad -> <=2-way on b128 writes
  __shared__ float  sB[CHUNK][17];
  {
    const int t0 = cc * CHUNK;
    int lin = tid * 4;                 // 4 elems per thread
    int tt = lin >> 4, dd = lin & 15;  // dd in {0,4,8,12}
    size_t m = (size_t)bb * LSEQ + t0 + tt;
    uint4 du4 = *(const uint4*)(dtu + m * DI + dblk * 16 + dd);
    f32x4 a, b2;
    a[0]  = bf2f((unsigned short)(du4.x >> 16)); a[1]  = bf2f((unsigned short)(du4.x & 0xffff));
    a[2]  = bf2f((unsigned short)(du4.y >> 16)); a[3]  = bf2f((unsigned short)(du4.y & 0xffff));
    b2[0] = bf2f((unsigned short)(du4.z >> 16)); b2[1] = bf2f((unsigned short)(du4.z & 0xffff));
    b2[2] = bf2f((unsigned short)(du4.w >> 16)); b2[3] = bf2f((unsigned short)(du4.w & 0xffff));
    *(f32x4*)&sdu[tt][dd]     = a;
    *(f32x4*)&sdu[tt][dd + 2] = b2;
    f32x4 Bv = *(const f32x4*)(dbcBC + m * 32 + dd);
    *(f32x4*)&sB[tt][dd] = Bv;
  }
  __syncthreads();
  float h = 0.f, dtsum = 0.f;
#pragma unroll 4
  for (int tt = 0; tt < CHUNK; ++tt) {
    float2 du = sdu[tt][di];
    float Bv  = sB[tt][s];
    h = fmaf(__expf(du.x * Ads), h, du.x * du.y * Bv);
    dtsum += du.x;
  }
  size_t ci = ((size_t)(bb * NC + cc) * DI + d);
  hend[ci * DS + s] = h;
  if (s == 0) Ssum[ci] = dtsum;
}

// Pass 2: sequential combine over chunks -> h_in per chunk. (tiny, 256 blocks)
__global__ __launch_bounds__(256) void scan_pass2(const float* __restrict__ A_log,
                                                  const float* __restrict__ hend,
                                                  const float* __restrict__ Ssum,
                                                  float* __restrict__ hin) {
  const int bb = blockIdx.x, dblk = blockIdx.y;
  const int tid = threadIdx.x;
  const int di = tid >> 4, s = tid & 15;
  const int d = dblk * 16 + di;
  const float Ads = -__expf(A_log[d * DS + s]);
  float h = 0.f;
  for (int cc = 0; cc < NC; ++cc) {
    size_t ci = ((size_t)(bb * NC + cc) * DI + d);
    hin[ci * DS + s] = h;
    h = fmaf(__expf(Ads * Ssum[ci]), h, hend[ci * DS + s]);
  }
}

// Pass 3: re-run each chunk from true h_in, fused gate epilogue -> yb (bf16).
__global__ __launch_bounds__(256) void scan_pass3(const unsigned int* __restrict__ dtu,
                                                  const float* __restrict__ dbcBC,
                                                  const unsigned short* __restrict__ xzb,
                                                  const float* __restrict__ A_log,
                                                  const float* __restrict__ D_skip,
                                                  const float* __restrict__ hin,
                                                  unsigned short* __restrict__ yb) {
  const int bb = blockIdx.x, dblk = blockIdx.y, cc = blockIdx.z;
  const int tid = threadIdx.x;
  const int di = tid >> 4, s = tid & 15;
  const int d = dblk * 16 + di;
  const float Ads = -__expf(A_log[d * DS + s]);

  __shared__ float2 sdu[CHUNK][18];   // (dt, u)
  __shared__ float2 sBC[CHUNK][18];   // (B, C)
  __shared__ float  sy[CHUNK][16];
  const int t0 = cc * CHUNK;
  const size_t mbase = (size_t)bb * LSEQ + t0;
  {
    int lin = tid * 4;
    int tt = lin >> 4, dd = lin & 15;   // dd in {0,4,8,12}
    size_t m = mbase + tt;
    uint4 du4 = *(const uint4*)(dtu + m * DI + dblk * 16 + dd);
    f32x4 a, b2;
    a[0]  = bf2f((unsigned short)(du4.x >> 16)); a[1]  = bf2f((unsigned short)(du4.x & 0xffff));
    a[2]  = bf2f((unsigned short)(du4.y >> 16)); a[3]  = bf2f((unsigned short)(du4.y & 0xffff));
    b2[0] = bf2f((unsigned short)(du4.z >> 16)); b2[1] = bf2f((unsigned short)(du4.z & 0xffff));
    b2[2] = bf2f((unsigned short)(du4.w >> 16)); b2[3] = bf2f((unsigned short)(du4.w & 0xffff));
    *(f32x4*)&sdu[tt][dd]     = a;
    *(f32x4*)&sdu[tt][dd + 2] = b2;
    f32x4 Bv = *(const f32x4*)(dbcBC + m * 32 + dd);
    f32x4 Cv = *(const f32x4*)(dbcBC + m * 32 + 16 + dd);
    f32x4 p0, p1;
    p0[0] = Bv[0]; p0[1] = Cv[0]; p0[2] = Bv[1]; p0[3] = Cv[1];
    p1[0] = Bv[2]; p1[1] = Cv[2]; p1[2] = Bv[3]; p1[3] = Cv[3];
    *(f32x4*)&sBC[tt][dd]     = p0;
    *(f32x4*)&sBC[tt][dd + 2] = p1;
  }
  __syncthreads();
  float h = hin[((size_t)(bb * NC + cc) * DI + d) * DS + s];
#pragma unroll 4
  for (int tt = 0; tt < CHUNK; ++tt) {
    float2 du = sdu[tt][di];
    float2 bc = sBC[tt][s];
    h = fmaf(__expf(du.x * Ads), h, du.x * du.y * bc.x);
    float v = dpp_sum16(h * bc.y);
    if (s == 0) sy[tt][di] = v;
  }
  __syncthreads();
#pragma unroll
  for (int q = 0; q < 4; ++q) {
    int lin = q * 256 + tid;
    int tt = lin >> 4, dd = lin & 15;
    size_t m = mbase + tt;
    float z = bf2f(xzb[m * 1024 + DI + dblk * 16 + dd]);   // direct global, coalesced
    float yv = sy[tt][dd] + sdu[tt][dd].y * D_skip[dblk * 16 + dd];
    yv *= z / (1.f + __expf(-z));
    yb[m * DI + dblk * 16 + dd] = f2bf(yv);
  }
}

// ---------------------------------------------------------------------------
extern "C" void kernel_launch(void* const* d_in, const int* in_sizes, int n_in,
                              void* d_out, int out_size, void* d_ws, size_t ws_size,
                              hipStream_t stream) {
  const float* x       = (const float*)d_in[0];
  const float* ln_g    = (const float*)d_in[1];
  const float* ln_b    = (const float*)d_in[2];
  const float* W_in    = (const float*)d_in[3];
  const float* conv_w  = (const float*)d_in[4];
  const float* conv_b  = (const float*)d_in[5];
  const float* W_xproj = (const float*)d_in[6];
  const float* W_dt    = (const float*)d_in[7];
  const float* b_dt    = (const float*)d_in[8];
  const float* A_log   = (const float*)d_in[9];
  const float* D_skip  = (const float*)d_in[10];
  const float* W_out   = (const float*)d_in[11];
  float* out = (float*)d_out;

  // Workspace layout
  float* ws    = (float*)d_ws;
  float* dbcBC = ws;                                    //   262,144 f
  float* hend  = dbcBC + (size_t)MROWS * 32;            // 1,048,576 f
  float* hin   = hend + (size_t)BATCH * NC * DI * DS;   // 1,048,576 f
  float* Ssum  = hin  + (size_t)BATCH * NC * DI * DS;   //    65,536 f
  unsigned int* dtu = (unsigned int*)(Ssum + (size_t)BATCH * NC * DI); // 4,194,304 u32
  unsigned short* xzb  = (unsigned short*)(dtu + (size_t)MROWS * DI); // 8,388,608 us
  unsigned short* yb   = xzb + (size_t)MROWS * 1024;    // 4,194,304 us
  unsigned short* xnb  = yb;   // alias: xnb dead before pass3 writes yb
  unsigned short* Wib  = yb  + (size_t)MROWS * DI;      // 262,144 us
  unsigned short* Wob  = Wib + (size_t)DIMC * 1024;     // 131,072 us
  unsigned short* Wxpb = Wob + (size_t)DI * DIMC;       //  32,768 us
  unsigned short* Wdtb = Wxpb + (size_t)64 * 512;       //  16,384 us

  // 0. prologue: weight prep + LayerNorm, one launch
  prologue<<<704, 256, 0, stream>>>(W_in, W_out, W_xproj, W_dt, x, ln_g, ln_b,
                                    Wib, Wob, Wxpb, Wdtb, xnb);

  // 1. xzb = bf16(xn @ W_in)   (8192x1024x256, bf16 MFMA, 128x128 tile)
  gemm_bf16_128<<<dim3(1024 / 128, MROWS / 128), 256, 0, stream>>>(
      xnb, Wib, xzb, MROWS, 1024, DIMC);

  // 2. fused: conv+SiLU (in LDS) ; dbcBC = (B|C) of u @ W_xproj ; dtu pack
  conv_xproj_dt<<<MROWS / 16, 256, 0, stream>>>(xzb, conv_w, conv_b,
                                                Wxpb, Wdtb, b_dt, dbcBC, dtu);

  // 3. chunked selective scan (3-pass form)
  dim3 gp13(BATCH, DI / 16, NC);
  dim3 gp2(BATCH, DI / 16);
  scan_pass1<<<gp13, 256, 0, stream>>>(dtu, dbcBC, A_log, hend, Ssum);
  scan_pass2<<<gp2, 256, 0, stream>>>(A_log, hend, Ssum, hin);
  scan_pass3<<<gp13, 256, 0, stream>>>(dtu, dbcBC, xzb, A_log, D_skip, hin, yb);

  // 4. out = yb @ W_out (64x64 tile, 512 blocks = 2/CU, +x residual)
  gemm_bf16_64<<<dim3(DIMC / 64, MROWS / 64), 256, 0, stream>>>(
      yb, Wob, out, MROWS, DIMC, DI, x);
}

// Round 10
// 179.552 us; speedup vs baseline: 1.7913x; 1.0153x over previous
//
#include <hip/hip_runtime.h>
#include <hip/hip_bf16.h>
#include <math.h>

// Problem constants
#define DIMC   256      // DIM
#define DI     512      // D_INNER
#define DS     16       // D_STATE
#define DTR    16       // DT_RANK
#define NX     48       // DT_RANK + 2*D_STATE
#define BATCH  8
#define LSEQ   1024     // H*W
#define MROWS  8192     // BATCH*LSEQ
#define CHUNK  64
#define NC     (LSEQ / CHUNK)   // 16 chunks

typedef __attribute__((ext_vector_type(8))) short short8;
typedef __attribute__((ext_vector_type(4))) float f32x4;

__device__ __forceinline__ unsigned short f2bf(float v) {
  __hip_bfloat16 h = __float2bfloat16(v);
  return *reinterpret_cast<unsigned short*>(&h);
}
__device__ __forceinline__ float bf2f(unsigned short u) {
  return __int_as_float(((int)u) << 16);
}

// Async global->LDS, 16B per lane. lds base must be wave-uniform; HW writes
// lane i's 16B to ldsbase + i*16 (m97 pattern).
__device__ __forceinline__ void load_lds16(const void* g, void* l) {
  __builtin_amdgcn_global_load_lds(
      (const __attribute__((address_space(1))) unsigned int*)g,
      (__attribute__((address_space(3))) unsigned int*)l, 16, 0, 0);
}

// Sum across the 16-lane group using DPP only (zero DS ops).
__device__ __forceinline__ float dpp_sum16(float v) {
  float t;
  t = __int_as_float(__builtin_amdgcn_mov_dpp(__float_as_int(v), 0xB1,  0xF, 0xF, true)); v += t; // ^1
  t = __int_as_float(__builtin_amdgcn_mov_dpp(__float_as_int(v), 0x4E,  0xF, 0xF, true)); v += t; // ^2
  t = __int_as_float(__builtin_amdgcn_mov_dpp(__float_as_int(v), 0x141, 0xF, 0xF, true)); v += t; // ^7 (row_half_mirror)
  t = __int_as_float(__builtin_amdgcn_mov_dpp(__float_as_int(v), 0x140, 0xF, 0xF, true)); v += t; // ^15 (row_mirror)
  return v;
}

// ---------------------------------------------------------------------------
// Prologue: weight prep + LayerNorm in ONE launch (branch on blockIdx.x).
// LN phase: 256 blocks (one per CU; was 128 = half the machine idle), each
// handling 32 l-positions. LDS 35KB (was 69KB).
__global__ __launch_bounds__(256) void prologue(const float* __restrict__ W_in,
                                                const float* __restrict__ W_out,
                                                const float* __restrict__ W_xproj,
                                                const float* __restrict__ W_dt,
                                                const float* __restrict__ x,
                                                const float* __restrict__ gamma,
                                                const float* __restrict__ beta,
                                                unsigned short* __restrict__ Wib,
                                                unsigned short* __restrict__ Wob,
                                                unsigned short* __restrict__ Wxpb,
                                                unsigned short* __restrict__ Wdtb,
                                                unsigned short* __restrict__ xnb) {
  __shared__ float sx[DIMC][33];
  __shared__ float2 spr[8][32];
  __shared__ float smean[32], srs[32];
  const int blk = blockIdx.x, tid = threadIdx.x;
  if (blk < 384) {
    float (*t)[33] = sx;
    const float* W; unsigned short* Wt; int K, N, bx, by;
    if (blk < 256) { W = W_in;  Wt = Wib; K = DIMC; N = 1024; bx = blk & 31; by = blk >> 5; }
    else           { W = W_out; Wt = Wob; K = DI;   N = DIMC; bx = (blk - 256) & 7; by = (blk - 256) >> 3; }
    int n0 = bx * 32, k0 = by * 32;
    int tx = tid & 31, ty = tid >> 5;
    for (int i = ty; i < 32; i += 8) t[i][tx] = W[(size_t)(k0 + i) * N + n0 + tx];
    __syncthreads();
    for (int i = ty; i < 32; i += 8)
      Wt[(size_t)(n0 + i) * K + k0 + tx] = f2bf(t[tx][i]);
    return;
  }
  if (blk < 512) {
    int idx = (blk - 384) * 256 + tid;   // < 64*512
    int n = idx >> 9, k = idx & 511;
    Wxpb[idx] = (n < NX) ? f2bf(W_xproj[(size_t)k * NX + n]) : (unsigned short)0;
    return;
  }
  if (blk < 576) {
    int idx = (blk - 512) * 256 + tid;   // < 512*32
    int n = idx >> 5, k = idx & 31;
    Wdtb[idx] = (k < DTR) ? f2bf(W_dt[(size_t)k * DI + n]) : (unsigned short)0;
    return;
  }
  // ---- LayerNorm: 256 blocks, 32 l-positions each ----
  const int lb = blk - 576;                 // 0..255
  const int b = lb >> 5, l0 = (lb & 31) * 32;
  {
    // Each thread loads its channel's 32 contiguous floats (128B).
    const float* p = x + ((size_t)b * DIMC + tid) * LSEQ + l0;
#pragma unroll
    for (int q = 0; q < 8; ++q) {
      float4 v = *(const float4*)(p + q * 4);
      sx[tid][q * 4 + 0] = v.x;
      sx[tid][q * 4 + 1] = v.y;
      sx[tid][q * 4 + 2] = v.z;
      sx[tid][q * 4 + 3] = v.w;
    }
  }
  __syncthreads();
  {
    // Stage 1: thread (cg,l) sums 32 channels for position l.
    const int l = tid & 31, cg = tid >> 5;
    float sum = 0.f, sq = 0.f;
#pragma unroll 8
    for (int cc = 0; cc < 32; ++cc) {
      float v = sx[cg * 32 + cc][l];
      sum += v; sq += v * v;
    }
    spr[cg][l] = make_float2(sum, sq);
  }
  __syncthreads();
  if (tid < 32) {
    float sum = 0.f, sq = 0.f;
#pragma unroll
    for (int g = 0; g < 8; ++g) { float2 p2 = spr[g][tid]; sum += p2.x; sq += p2.y; }
    float mean = sum * (1.f / 256.f);
    float var  = sq * (1.f / 256.f) - mean * mean;
    smean[tid] = mean; srs[tid] = rsqrtf(var + 1e-5f);
  }
  __syncthreads();
  {
    const float gg = gamma[tid], bb = beta[tid];
    const size_t base = ((size_t)b * LSEQ + l0) * DIMC + tid;
#pragma unroll 4
    for (int ll = 0; ll < 32; ++ll) {
      float v = (sx[tid][ll] - smean[ll]) * srs[ll] * gg + bb;
      xnb[base + (size_t)ll * DIMC] = f2bf(v);
    }
  }
}

// ---------------------------------------------------------------------------
// bf16 MFMA GEMM, m97 structure: 128x128 tile, 4x4 acc/wave, BK=32.
// C(bf16 [M][N]) = A(bf16 [M][K]) * Bt(bf16 [N][K])^T.  (used for gemm1)
__global__ __launch_bounds__(256) void gemm_bf16_128(const unsigned short* __restrict__ A,
                                                     const unsigned short* __restrict__ Bt,
                                                     unsigned short* __restrict__ Cb,
                                                     int M, int N, int K) {
  __shared__ unsigned short As[128][32];
  __shared__ unsigned short Bs[128][32];
  const int tid = threadIdx.x;
  const int lane = tid & 63, wave = tid >> 6;
  const int wm = wave >> 1, wn = wave & 1;
  const int quad = lane >> 4, l16 = lane & 15;
  const int m0 = blockIdx.y * 128, n0 = blockIdx.x * 128;

  f32x4 acc[4][4];
#pragma unroll
  for (int i = 0; i < 4; ++i)
#pragma unroll
    for (int j = 0; j < 4; ++j) acc[i][j] = (f32x4){0.f, 0.f, 0.f, 0.f};

  for (int k0 = 0; k0 < K; k0 += 32) {
    // A tile: 512 chunks of 16B (2/thread); LDS offset = id*16 (linear).
#pragma unroll
    for (int q = 0; q < 2; ++q) {
      int id = q * 256 + tid;
      int row = id >> 2, c = id & 3;
      load_lds16(A + (size_t)(m0 + row) * K + k0 + c * 8,
                 (char*)&As[0][0] + (size_t)(q * 256 + wave * 64) * 16);
    }
    // B tile: 512 chunks (2/thread).
#pragma unroll
    for (int q = 0; q < 2; ++q) {
      int id = q * 256 + tid;
      int row = id >> 2, c = id & 3;
      load_lds16(Bt + (size_t)(n0 + row) * K + k0 + c * 8,
                 (char*)&Bs[0][0] + (size_t)(q * 256 + wave * 64) * 16);
    }
    __syncthreads();   // drains vmcnt before LDS reads
    short8 af[4], bfr[4];
#pragma unroll
    for (int i = 0; i < 4; ++i)
      af[i] = *(const short8*)&As[wm * 64 + i * 16 + l16][quad * 8];
#pragma unroll
    for (int j = 0; j < 4; ++j)
      bfr[j] = *(const short8*)&Bs[wn * 64 + j * 16 + l16][quad * 8];
#pragma unroll
    for (int i = 0; i < 4; ++i)
#pragma unroll
      for (int j = 0; j < 4; ++j)
        acc[i][j] = __builtin_amdgcn_mfma_f32_16x16x32_bf16(af[i], bfr[j], acc[i][j], 0, 0, 0);
    __syncthreads();
  }

#pragma unroll
  for (int i = 0; i < 4; ++i) {
    int rowb = wm * 64 + i * 16 + quad * 4;
#pragma unroll
    for (int j = 0; j < 4; ++j) {
      int n = n0 + wn * 64 + j * 16 + l16;
#pragma unroll
      for (int r = 0; r < 4; ++r)
        Cb[(size_t)(m0 + rowb + r) * N + n] = f2bf(acc[i][j][r]);
    }
  }
}

// ---------------------------------------------------------------------------
// bf16 MFMA GEMM, 64x64 tile, BK=64, fused transpose+residual epilogue.
// Used for gemm2 (M=8192, N=256, K=512): grid (N/64, M/64) = 512 blocks
// = 2 blocks/CU (vs 1 for the old 128x64 tile) -> 2x occupancy.
// out[b*DIMC*LSEQ + n*LSEQ + l] = acc + X.
__global__ __launch_bounds__(256) void gemm_bf16_64(const unsigned short* __restrict__ A,
                                                    const unsigned short* __restrict__ Bt,
                                                    float* __restrict__ C,
                                                    int M, int N, int K,
                                                    const float* __restrict__ X) {
  __shared__ unsigned short As[64][64];
  __shared__ unsigned short Bs[64][64];
  const int tid = threadIdx.x;
  const int lane = tid & 63, wave = tid >> 6;
  const int wm = wave >> 1, wn = wave & 1;
  const int quad = lane >> 4, l16 = lane & 15;
  const int m0 = blockIdx.y * 64, n0 = blockIdx.x * 64;

  f32x4 acc[2][2];
#pragma unroll
  for (int i = 0; i < 2; ++i)
#pragma unroll
    for (int j = 0; j < 2; ++j) acc[i][j] = (f32x4){0.f, 0.f, 0.f, 0.f};

  for (int k0 = 0; k0 < K; k0 += 64) {
    // A tile 64x64: 512 chunks of 16B (2/thread); row = id>>3, c8 = id&7.
#pragma unroll
    for (int q = 0; q < 2; ++q) {
      int id = q * 256 + tid;
      int row = id >> 3, c = id & 7;
      load_lds16(A + (size_t)(m0 + row) * K + k0 + c * 8,
                 (char*)&As[0][0] + (size_t)(q * 256 + wave * 64) * 16);
    }
#pragma unroll
    for (int q = 0; q < 2; ++q) {
      int id = q * 256 + tid;
      int row = id >> 3, c = id & 7;
      load_lds16(Bt + (size_t)(n0 + row) * K + k0 + c * 8,
                 (char*)&Bs[0][0] + (size_t)(q * 256 + wave * 64) * 16);
    }
    __syncthreads();   // drains vmcnt before LDS reads
#pragma unroll
    for (int kk = 0; kk < 64; kk += 32) {
      short8 af[2], bfr[2];
#pragma unroll
      for (int i = 0; i < 2; ++i)
        af[i] = *(const short8*)&As[wm * 32 + i * 16 + l16][kk + quad * 8];
#pragma unroll
      for (int j = 0; j < 2; ++j)
        bfr[j] = *(const short8*)&Bs[wn * 32 + j * 16 + l16][kk + quad * 8];
#pragma unroll
      for (int i = 0; i < 2; ++i)
#pragma unroll
        for (int j = 0; j < 2; ++j)
          acc[i][j] = __builtin_amdgcn_mfma_f32_16x16x32_bf16(af[i], bfr[j], acc[i][j], 0, 0, 0);
    }
    __syncthreads();
  }

#pragma unroll
  for (int i = 0; i < 2; ++i) {
    int m = m0 + wm * 32 + i * 16 + quad * 4;
    int b = m >> 10, l = m & 1023;
#pragma unroll
    for (int j = 0; j < 2; ++j) {
      int n = n0 + wn * 32 + j * 16 + l16;
      size_t o = (size_t)b * (DIMC * LSEQ) + (size_t)n * LSEQ + l;
      f32x4 xv = *(const f32x4*)(X + o);
      f32x4 rv = acc[i][j] + xv;
      *(f32x4*)(C + o) = rv;
    }
  }
}

// ---------------------------------------------------------------------------
// Fused conv + SiLU + xproj + dt (MFMA).
// m-tile 16, grid 512 (2 blocks/CU co-resident = 2 waves/SIMD).
// xproj uses TWO independent MFMA accumulator chains (k halves) for 2x ILP.
__global__ __launch_bounds__(256) void conv_xproj_dt(
    const unsigned short* __restrict__ xzb,
    const float* __restrict__ conv_w,
    const float* __restrict__ conv_b,
    const unsigned short* __restrict__ Wxpb,
    const unsigned short* __restrict__ Wdtb,
    const float* __restrict__ b_dt,
    float* __restrict__ dbcBC,
    unsigned int* __restrict__ dtu) {
  __shared__ unsigned short sxz[19][512];       // 16 rows + 3 halo
  __shared__ unsigned short su[16][512 + 8];
  __shared__ unsigned short sdbc[16][40];
  const int m0 = blockIdx.x * 16;
  const int l0 = m0 & 1023;
  const int tid = threadIdx.x, lane = tid & 63, w = tid >> 6;
  const int quad = lane >> 4, l16 = lane & 15;

  // Stage the xz u-half tile with halo: 19*64 = 1216 chunks of 8 bf16.
#pragma unroll
  for (int q = 0; q < 5; ++q) {
    int id = q * 256 + tid;
    if (id < 19 * 64) {
      int rr = id >> 6, c8 = id & 63;
      uint4 v; v.x = 0u; v.y = 0u; v.z = 0u; v.w = 0u;
      if (l0 - 3 + rr >= 0)
        v = *(const uint4*)(xzb + (size_t)(m0 - 3 + rr) * 1024 + c8 * 8);
      *(uint4*)&sxz[rr][c8 * 8] = v;
    }
  }
  __syncthreads();

  // conv(k=4) + bias + SiLU -> su (32 outputs/thread, coalesced in c).
#pragma unroll 4
  for (int q = 0; q < 32; ++q) {
    int idx = q * 256 + tid;
    int r = idx >> 9, c = idx & 511;
    float4 wv = *(const float4*)(conv_w + c * 4);
    float acc = conv_b[c];
    acc = fmaf(bf2f(sxz[r + 0][c]), wv.x, acc);
    acc = fmaf(bf2f(sxz[r + 1][c]), wv.y, acc);
    acc = fmaf(bf2f(sxz[r + 2][c]), wv.z, acc);
    acc = fmaf(bf2f(sxz[r + 3][c]), wv.w, acc);
    float u = acc / (1.f + __expf(-acc));
    su[r][c] = f2bf(u);
  }
  __syncthreads();

  // xproj MFMA: A-frags from su, B-frags from global (L2-hot).
  // Two independent accumulator chains over k halves -> 2x MFMA ILP.
  f32x4 acc0 = (f32x4){0.f, 0.f, 0.f, 0.f};
  f32x4 acc1 = (f32x4){0.f, 0.f, 0.f, 0.f};
#pragma unroll 4
  for (int k0 = 0; k0 < 256; k0 += 32) {
    short8 afA = *(const short8*)&su[l16][k0 + quad * 8];
    short8 bfA = *(const short8*)(Wxpb + (size_t)(w * 16 + l16) * 512 + k0 + quad * 8);
    acc0 = __builtin_amdgcn_mfma_f32_16x16x32_bf16(afA, bfA, acc0, 0, 0, 0);
    short8 afB = *(const short8*)&su[l16][256 + k0 + quad * 8];
    short8 bfB = *(const short8*)(Wxpb + (size_t)(w * 16 + l16) * 512 + 256 + k0 + quad * 8);
    acc1 = __builtin_amdgcn_mfma_f32_16x16x32_bf16(afB, bfB, acc1, 0, 0, 0);
  }
  f32x4 acc = acc0 + acc1;
  // Persist only B (n=16..31) and C (n=32..47) columns.
  if (w == 1 || w == 2) {
#pragma unroll
    for (int r = 0; r < 4; ++r)
      dbcBC[(size_t)(m0 + quad * 4 + r) * 32 + (w - 1) * 16 + l16] = acc[r];
  }
  if (w < 2) {
#pragma unroll
    for (int r = 0; r < 4; ++r)
      sdbc[quad * 4 + r][w * 16 + l16] = f2bf(acc[r]);
  }
  __syncthreads();

  // dt MFMA + softplus + dtu pack (u pulled from su).
  short8 af0 = *(const short8*)&sdbc[l16][quad * 8];
#pragma unroll
  for (int jn = 0; jn < 8; ++jn) {
    const int n0 = w * 128 + jn * 16;
    short8 bf = *(const short8*)(Wdtb + (size_t)(n0 + l16) * 32 + quad * 8);
    f32x4 a0 = (f32x4){0.f, 0.f, 0.f, 0.f};
    a0 = __builtin_amdgcn_mfma_f32_16x16x32_bf16(af0, bf, a0, 0, 0, 0);
    const float bd = b_dt[n0 + l16];
#pragma unroll
    for (int r = 0; r < 4; ++r) {
      int lr0 = quad * 4 + r;
      float v = a0[r] + bd;
      float sp = (v > 20.f) ? v : log1pf(__expf(v));
      unsigned int u0 = (unsigned int)su[lr0][n0 + l16];
      dtu[(size_t)(m0 + lr0) * DI + n0 + l16] = u0 | ((unsigned int)f2bf(sp) << 16);
    }
  }
}

// ---------------------------------------------------------------------------
// Chunked selective scan, (d,s) LDS-staged layout.
// Pass 1: local scan from h=0 -> hend, sum dt. Grid (BATCH, 32, NC).
__global__ __launch_bounds__(256) void scan_pass1(const unsigned int* __restrict__ dtu,
                                                  const float* __restrict__ dbcBC,
                                                  const float* __restrict__ A_log,
                                                  float* __restrict__ hend,
                                                  float* __restrict__ Ssum) {
  const int bb = blockIdx.x, dblk = blockIdx.y, cc = blockIdx.z;
  const int tid = threadIdx.x;
  const int di = tid >> 4, s = tid & 15;
  const int d = dblk * 16 + di;
  const float Ads = -__expf(A_log[d * DS + s]);

  __shared__ float2 sdu[CHUNK][18];   // (dt, u); pad -> <=2-way on b128 writes
  __shared__ float  sB[CHUNK][17];
  {
    const int t0 = cc * CHUNK;
    int lin = tid * 4;                 // 4 elems per thread
    int tt = lin >> 4, dd = lin & 15;  // dd in {0,4,8,12}
    size_t m = (size_t)bb * LSEQ + t0 + tt;
    uint4 du4 = *(const uint4*)(dtu + m * DI + dblk * 16 + dd);
    f32x4 a, b2;
    a[0]  = bf2f((unsigned short)(du4.x >> 16)); a[1]  = bf2f((unsigned short)(du4.x & 0xffff));
    a[2]  = bf2f((unsigned short)(du4.y >> 16)); a[3]  = bf2f((unsigned short)(du4.y & 0xffff));
    b2[0] = bf2f((unsigned short)(du4.z >> 16)); b2[1] = bf2f((unsigned short)(du4.z & 0xffff));
    b2[2] = bf2f((unsigned short)(du4.w >> 16)); b2[3] = bf2f((unsigned short)(du4.w & 0xffff));
    *(f32x4*)&sdu[tt][dd]     = a;
    *(f32x4*)&sdu[tt][dd + 2] = b2;
    f32x4 Bv = *(const f32x4*)(dbcBC + m * 32 + dd);
    *(f32x4*)&sB[tt][dd] = Bv;
  }
  __syncthreads();
  float h = 0.f, dtsum = 0.f;
#pragma unroll 4
  for (int tt = 0; tt < CHUNK; ++tt) {
    float2 du = sdu[tt][di];
    float Bv  = sB[tt][s];
    h = fmaf(__expf(du.x * Ads), h, du.x * du.y * Bv);
    dtsum += du.x;
  }
  size_t ci = ((size_t)(bb * NC + cc) * DI + d);
  hend[ci * DS + s] = h;
  if (s == 0) Ssum[ci] = dtsum;
}

// Pass 2: sequential combine over chunks -> h_in per chunk. (tiny, 256 blocks)
__global__ __launch_bounds__(256) void scan_pass2(const float* __restrict__ A_log,
                                                  const float* __restrict__ hend,
                                                  const float* __restrict__ Ssum,
                                                  float* __restrict__ hin) {
  const int bb = blockIdx.x, dblk = blockIdx.y;
  const int tid = threadIdx.x;
  const int di = tid >> 4, s = tid & 15;
  const int d = dblk * 16 + di;
  const float Ads = -__expf(A_log[d * DS + s]);
  float h = 0.f;
  for (int cc = 0; cc < NC; ++cc) {
    size_t ci = ((size_t)(bb * NC + cc) * DI + d);
    hin[ci * DS + s] = h;
    h = fmaf(__expf(Ads * Ssum[ci]), h, hend[ci * DS + s]);
  }
}

// Pass 3: re-run each chunk from true h_in, fused gate epilogue -> yb (bf16).
__global__ __launch_bounds__(256) void scan_pass3(const unsigned int* __restrict__ dtu,
                                                  const float* __restrict__ dbcBC,
                                                  const unsigned short* __restrict__ xzb,
                                                  const float* __restrict__ A_log,
                                                  const float* __restrict__ D_skip,
                                                  const float* __restrict__ hin,
                                                  unsigned short* __restrict__ yb) {
  const int bb = blockIdx.x, dblk = blockIdx.y, cc = blockIdx.z;
  const int tid = threadIdx.x;
  const int di = tid >> 4, s = tid & 15;
  const int d = dblk * 16 + di;
  const float Ads = -__expf(A_log[d * DS + s]);

  __shared__ float2 sdu[CHUNK][18];   // (dt, u)
  __shared__ float2 sBC[CHUNK][18];   // (B, C)
  __shared__ float  sy[CHUNK][16];
  const int t0 = cc * CHUNK;
  const size_t mbase = (size_t)bb * LSEQ + t0;
  {
    int lin = tid * 4;
    int tt = lin >> 4, dd = lin & 15;   // dd in {0,4,8,12}
    size_t m = mbase + tt;
    uint4 du4 = *(const uint4*)(dtu + m * DI + dblk * 16 + dd);
    f32x4 a, b2;
    a[0]  = bf2f((unsigned short)(du4.x >> 16)); a[1]  = bf2f((unsigned short)(du4.x & 0xffff));
    a[2]  = bf2f((unsigned short)(du4.y >> 16)); a[3]  = bf2f((unsigned short)(du4.y & 0xffff));
    b2[0] = bf2f((unsigned short)(du4.z >> 16)); b2[1] = bf2f((unsigned short)(du4.z & 0xffff));
    b2[2] = bf2f((unsigned short)(du4.w >> 16)); b2[3] = bf2f((unsigned short)(du4.w & 0xffff));
    *(f32x4*)&sdu[tt][dd]     = a;
    *(f32x4*)&sdu[tt][dd + 2] = b2;
    f32x4 Bv = *(const f32x4*)(dbcBC + m * 32 + dd);
    f32x4 Cv = *(const f32x4*)(dbcBC + m * 32 + 16 + dd);
    f32x4 p0, p1;
    p0[0] = Bv[0]; p0[1] = Cv[0]; p0[2] = Bv[1]; p0[3] = Cv[1];
    p1[0] = Bv[2]; p1[1] = Cv[2]; p1[2] = Bv[3]; p1[3] = Cv[3];
    *(f32x4*)&sBC[tt][dd]     = p0;
    *(f32x4*)&sBC[tt][dd + 2] = p1;
  }
  __syncthreads();
  float h = hin[((size_t)(bb * NC + cc) * DI + d) * DS + s];
#pragma unroll 4
  for (int tt = 0; tt < CHUNK; ++tt) {
    float2 du = sdu[tt][di];
    float2 bc = sBC[tt][s];
    h = fmaf(__expf(du.x * Ads), h, du.x * du.y * bc.x);
    float v = dpp_sum16(h * bc.y);
    if (s == 0) sy[tt][di] = v;
  }
  __syncthreads();
#pragma unroll
  for (int q = 0; q < 4; ++q) {
    int lin = q * 256 + tid;
    int tt = lin >> 4, dd = lin & 15;
    size_t m = mbase + tt;
    float z = bf2f(xzb[m * 1024 + DI + dblk * 16 + dd]);   // direct global, coalesced
    float yv = sy[tt][dd] + sdu[tt][dd].y * D_skip[dblk * 16 + dd];
    yv *= z / (1.f + __expf(-z));
    yb[m * DI + dblk * 16 + dd] = f2bf(yv);
  }
}

// ---------------------------------------------------------------------------
extern "C" void kernel_launch(void* const* d_in, const int* in_sizes, int n_in,
                              void* d_out, int out_size, void* d_ws, size_t ws_size,
                              hipStream_t stream) {
  const float* x       = (const float*)d_in[0];
  const float* ln_g    = (const float*)d_in[1];
  const float* ln_b    = (const float*)d_in[2];
  const float* W_in    = (const float*)d_in[3];
  const float* conv_w  = (const float*)d_in[4];
  const float* conv_b  = (const float*)d_in[5];
  const float* W_xproj = (const float*)d_in[6];
  const float* W_dt    = (const float*)d_in[7];
  const float* b_dt    = (const float*)d_in[8];
  const float* A_log   = (const float*)d_in[9];
  const float* D_skip  = (const float*)d_in[10];
  const float* W_out   = (const float*)d_in[11];
  float* out = (float*)d_out;

  // Workspace layout
  float* ws    = (float*)d_ws;
  float* dbcBC = ws;                                    //   262,144 f
  float* hend  = dbcBC + (size_t)MROWS * 32;            // 1,048,576 f
  float* hin   = hend + (size_t)BATCH * NC * DI * DS;   // 1,048,576 f
  float* Ssum  = hin  + (size_t)BATCH * NC * DI * DS;   //    65,536 f
  unsigned int* dtu = (unsigned int*)(Ssum + (size_t)BATCH * NC * DI); // 4,194,304 u32
  unsigned short* xzb  = (unsigned short*)(dtu + (size_t)MROWS * DI); // 8,388,608 us
  unsigned short* yb   = xzb + (size_t)MROWS * 1024;    // 4,194,304 us
  unsigned short* xnb  = yb;   // alias: xnb dead before pass3 writes yb
  unsigned short* Wib  = yb  + (size_t)MROWS * DI;      // 262,144 us
  unsigned short* Wob  = Wib + (size_t)DIMC * 1024;     // 131,072 us
  unsigned short* Wxpb = Wob + (size_t)DI * DIMC;       //  32,768 us
  unsigned short* Wdtb = Wxpb + (size_t)64 * 512;       //  16,384 us

  // 0. prologue: weight prep + LayerNorm (256 LN blocks), one launch
  prologue<<<832, 256, 0, stream>>>(W_in, W_out, W_xproj, W_dt, x, ln_g, ln_b,
                                    Wib, Wob, Wxpb, Wdtb, xnb);

  // 1. xzb = bf16(xn @ W_in)   (8192x1024x256, bf16 MFMA, 128x128 tile)
  gemm_bf16_128<<<dim3(1024 / 128, MROWS / 128), 256, 0, stream>>>(
      xnb, Wib, xzb, MROWS, 1024, DIMC);

  // 2. fused: conv+SiLU (in LDS) ; dbcBC = (B|C) of u @ W_xproj ; dtu pack
  conv_xproj_dt<<<MROWS / 16, 256, 0, stream>>>(xzb, conv_w, conv_b,
                                                Wxpb, Wdtb, b_dt, dbcBC, dtu);

  // 3. chunked selective scan (3-pass form)
  dim3 gp13(BATCH, DI / 16, NC);
  dim3 gp2(BATCH, DI / 16);
  scan_pass1<<<gp13, 256, 0, stream>>>(dtu, dbcBC, A_log, hend, Ssum);
  scan_pass2<<<gp2, 256, 0, stream>>>(A_log, hend, Ssum, hin);
  scan_pass3<<<gp13, 256, 0, stream>>>(dtu, dbcBC, xzb, A_log, D_skip, hin, yb);

  // 4. out = yb @ W_out (64x64 tile, 512 blocks = 2/CU, +x residual)
  gemm_bf16_64<<<dim3(DIMC / 64, MROWS / 64), 256, 0, stream>>>(
      yb, Wob, out, MROWS, DIMC, DI, x);
}

// Round 11
// 178.288 us; speedup vs baseline: 1.8040x; 1.0071x over previous
//
#include <hip/hip_runtime.h>
#include <hip/hip_bf16.h>
#include <math.h>

// Problem constants
#define DIMC   256      // DIM
#define DI     512      // D_INNER
#define DS     16       // D_STATE
#define DTR    16       // DT_RANK
#define NX     48       // DT_RANK + 2*D_STATE
#define BATCH  8
#define LSEQ   1024     // H*W
#define MROWS  8192     // BATCH*LSEQ
#define CHUNK  64
#define NC     (LSEQ / CHUNK)   // 16 chunks

typedef __attribute__((ext_vector_type(8))) short short8;
typedef __attribute__((ext_vector_type(4))) float f32x4;

__device__ __forceinline__ unsigned short f2bf(float v) {
  __hip_bfloat16 h = __float2bfloat16(v);
  return *reinterpret_cast<unsigned short*>(&h);
}
__device__ __forceinline__ float bf2f(unsigned short u) {
  return __int_as_float(((int)u) << 16);
}

// Async global->LDS, 16B per lane. lds base must be wave-uniform; HW writes
// lane i's 16B to ldsbase + i*16 (m97 pattern).
__device__ __forceinline__ void load_lds16(const void* g, void* l) {
  __builtin_amdgcn_global_load_lds(
      (const __attribute__((address_space(1))) unsigned int*)g,
      (__attribute__((address_space(3))) unsigned int*)l, 16, 0, 0);
}

// Sum across the 16-lane group using DPP only (zero DS ops).
__device__ __forceinline__ float dpp_sum16(float v) {
  float t;
  t = __int_as_float(__builtin_amdgcn_mov_dpp(__float_as_int(v), 0xB1,  0xF, 0xF, true)); v += t; // ^1
  t = __int_as_float(__builtin_amdgcn_mov_dpp(__float_as_int(v), 0x4E,  0xF, 0xF, true)); v += t; // ^2
  t = __int_as_float(__builtin_amdgcn_mov_dpp(__float_as_int(v), 0x141, 0xF, 0xF, true)); v += t; // ^7 (row_half_mirror)
  t = __int_as_float(__builtin_amdgcn_mov_dpp(__float_as_int(v), 0x140, 0xF, 0xF, true)); v += t; // ^15 (row_mirror)
  return v;
}

// ---------------------------------------------------------------------------
// Prologue: weight prep + LayerNorm in ONE launch (branch on blockIdx.x).
// LN phase: 256 blocks (one per CU), each handling 32 l-positions. LDS 35KB.
__global__ __launch_bounds__(256) void prologue(const float* __restrict__ W_in,
                                                const float* __restrict__ W_out,
                                                const float* __restrict__ W_xproj,
                                                const float* __restrict__ W_dt,
                                                const float* __restrict__ x,
                                                const float* __restrict__ gamma,
                                                const float* __restrict__ beta,
                                                unsigned short* __restrict__ Wib,
                                                unsigned short* __restrict__ Wob,
                                                unsigned short* __restrict__ Wxpb,
                                                unsigned short* __restrict__ Wdtb,
                                                unsigned short* __restrict__ xnb) {
  __shared__ float sx[DIMC][33];
  __shared__ float2 spr[8][32];
  __shared__ float smean[32], srs[32];
  const int blk = blockIdx.x, tid = threadIdx.x;
  if (blk < 384) {
    float (*t)[33] = sx;
    const float* W; unsigned short* Wt; int K, N, bx, by;
    if (blk < 256) { W = W_in;  Wt = Wib; K = DIMC; N = 1024; bx = blk & 31; by = blk >> 5; }
    else           { W = W_out; Wt = Wob; K = DI;   N = DIMC; bx = (blk - 256) & 7; by = (blk - 256) >> 3; }
    int n0 = bx * 32, k0 = by * 32;
    int tx = tid & 31, ty = tid >> 5;
    for (int i = ty; i < 32; i += 8) t[i][tx] = W[(size_t)(k0 + i) * N + n0 + tx];
    __syncthreads();
    for (int i = ty; i < 32; i += 8)
      Wt[(size_t)(n0 + i) * K + k0 + tx] = f2bf(t[tx][i]);
    return;
  }
  if (blk < 512) {
    int idx = (blk - 384) * 256 + tid;   // < 64*512
    int n = idx >> 9, k = idx & 511;
    Wxpb[idx] = (n < NX) ? f2bf(W_xproj[(size_t)k * NX + n]) : (unsigned short)0;
    return;
  }
  if (blk < 576) {
    int idx = (blk - 512) * 256 + tid;   // < 512*32
    int n = idx >> 5, k = idx & 31;
    Wdtb[idx] = (k < DTR) ? f2bf(W_dt[(size_t)k * DI + n]) : (unsigned short)0;
    return;
  }
  // ---- LayerNorm: 256 blocks, 32 l-positions each ----
  const int lb = blk - 576;                 // 0..255
  const int b = lb >> 5, l0 = (lb & 31) * 32;
  {
    // Each thread loads its channel's 32 contiguous floats (128B).
    const float* p = x + ((size_t)b * DIMC + tid) * LSEQ + l0;
#pragma unroll
    for (int q = 0; q < 8; ++q) {
      float4 v = *(const float4*)(p + q * 4);
      sx[tid][q * 4 + 0] = v.x;
      sx[tid][q * 4 + 1] = v.y;
      sx[tid][q * 4 + 2] = v.z;
      sx[tid][q * 4 + 3] = v.w;
    }
  }
  __syncthreads();
  {
    // Stage 1: thread (cg,l) sums 32 channels for position l.
    const int l = tid & 31, cg = tid >> 5;
    float sum = 0.f, sq = 0.f;
#pragma unroll 8
    for (int cc = 0; cc < 32; ++cc) {
      float v = sx[cg * 32 + cc][l];
      sum += v; sq += v * v;
    }
    spr[cg][l] = make_float2(sum, sq);
  }
  __syncthreads();
  if (tid < 32) {
    float sum = 0.f, sq = 0.f;
#pragma unroll
    for (int g = 0; g < 8; ++g) { float2 p2 = spr[g][tid]; sum += p2.x; sq += p2.y; }
    float mean = sum * (1.f / 256.f);
    float var  = sq * (1.f / 256.f) - mean * mean;
    smean[tid] = mean; srs[tid] = rsqrtf(var + 1e-5f);
  }
  __syncthreads();
  {
    const float gg = gamma[tid], bb = beta[tid];
    const size_t base = ((size_t)b * LSEQ + l0) * DIMC + tid;
#pragma unroll 4
    for (int ll = 0; ll < 32; ++ll) {
      float v = (sx[tid][ll] - smean[ll]) * srs[ll] * gg + bb;
      xnb[base + (size_t)ll * DIMC] = f2bf(v);
    }
  }
}

// ---------------------------------------------------------------------------
// bf16 MFMA GEMM, 128x64 tile, BK=32, bf16 C out.  Used for gemm1.
// Grid (N/64, M/128) = (16, 64) = 1024 blocks = 4 blocks/CU (was 2 at 128^2).
// K=256 is only 8 K-steps -> latency-bound; TLP beats MFMA density here
// (same mechanism as gemm2's 64-tile win in r8).
__global__ __launch_bounds__(256, 4) void gemm_bf16_m128n64(
    const unsigned short* __restrict__ A,
    const unsigned short* __restrict__ Bt,
    unsigned short* __restrict__ Cb,
    int M, int N, int K) {
  __shared__ unsigned short As[128][32];
  __shared__ unsigned short Bs[64][32];
  const int tid = threadIdx.x;
  const int lane = tid & 63, wave = tid >> 6;
  const int wm = wave >> 1, wn = wave & 1;
  const int quad = lane >> 4, l16 = lane & 15;
  const int m0 = blockIdx.y * 128, n0 = blockIdx.x * 64;

  f32x4 acc[4][2];
#pragma unroll
  for (int i = 0; i < 4; ++i)
#pragma unroll
    for (int j = 0; j < 2; ++j) acc[i][j] = (f32x4){0.f, 0.f, 0.f, 0.f};

  for (int k0 = 0; k0 < K; k0 += 32) {
    // A tile: 512 chunks of 16B (2/thread); LDS offset = id*16 (linear).
#pragma unroll
    for (int q = 0; q < 2; ++q) {
      int id = q * 256 + tid;
      int row = id >> 2, c = id & 3;
      load_lds16(A + (size_t)(m0 + row) * K + k0 + c * 8,
                 (char*)&As[0][0] + (size_t)(q * 256 + wave * 64) * 16);
    }
    // B tile: 256 chunks (1/thread).
    {
      int row = tid >> 2, c = tid & 3;
      load_lds16(Bt + (size_t)(n0 + row) * K + k0 + c * 8,
                 (char*)&Bs[0][0] + (size_t)(wave * 64) * 16);
    }
    __syncthreads();   // drains vmcnt before LDS reads
    short8 af[4], bfrag[2];
#pragma unroll
    for (int i = 0; i < 4; ++i)
      af[i] = *(const short8*)&As[wm * 64 + i * 16 + l16][quad * 8];
#pragma unroll
    for (int j = 0; j < 2; ++j)
      bfrag[j] = *(const short8*)&Bs[wn * 32 + j * 16 + l16][quad * 8];
#pragma unroll
    for (int i = 0; i < 4; ++i)
#pragma unroll
      for (int j = 0; j < 2; ++j)
        acc[i][j] = __builtin_amdgcn_mfma_f32_16x16x32_bf16(af[i], bfrag[j], acc[i][j], 0, 0, 0);
    __syncthreads();
  }

#pragma unroll
  for (int i = 0; i < 4; ++i) {
    int rowb = wm * 64 + i * 16 + quad * 4;
#pragma unroll
    for (int j = 0; j < 2; ++j) {
      int n = n0 + wn * 32 + j * 16 + l16;
#pragma unroll
      for (int r = 0; r < 4; ++r)
        Cb[(size_t)(m0 + rowb + r) * N + n] = f2bf(acc[i][j][r]);
    }
  }
}

// ---------------------------------------------------------------------------
// bf16 MFMA GEMM, 32x64 tile, BK=64, fused transpose+residual epilogue.
// Used for gemm2 (M=8192, N=256, K=512): grid (N/64, M/32) = (4, 256) =
// 1024 blocks = 4 blocks/CU (was 2 at 64x64). K-order = ascending 32-chunks,
// identical to before -> bit-identical output.
// out[b*DIMC*LSEQ + n*LSEQ + l] = acc + X.
__global__ __launch_bounds__(256, 4) void gemm_bf16_m32n64(
    const unsigned short* __restrict__ A,
    const unsigned short* __restrict__ Bt,
    float* __restrict__ C,
    int M, int N, int K,
    const float* __restrict__ X) {
  __shared__ unsigned short As[32][64];
  __shared__ unsigned short Bs[64][64];
  const int tid = threadIdx.x;
  const int lane = tid & 63, wave = tid >> 6;
  const int wm = wave >> 1, wn = wave & 1;
  const int quad = lane >> 4, l16 = lane & 15;
  const int m0 = blockIdx.y * 32, n0 = blockIdx.x * 64;

  f32x4 acc[2];
  acc[0] = (f32x4){0.f, 0.f, 0.f, 0.f};
  acc[1] = (f32x4){0.f, 0.f, 0.f, 0.f};

  for (int k0 = 0; k0 < K; k0 += 64) {
    // A tile 32x64: 256 chunks of 16B (1/thread); row = id>>3, c = id&7.
    {
      int row = tid >> 3, c = tid & 7;
      load_lds16(A + (size_t)(m0 + row) * K + k0 + c * 8,
                 (char*)&As[0][0] + (size_t)(wave * 64) * 16);
    }
    // B tile 64x64: 512 chunks (2/thread).
#pragma unroll
    for (int q = 0; q < 2; ++q) {
      int id = q * 256 + tid;
      int row = id >> 3, c = id & 7;
      load_lds16(Bt + (size_t)(n0 + row) * K + k0 + c * 8,
                 (char*)&Bs[0][0] + (size_t)(q * 256 + wave * 64) * 16);
    }
    __syncthreads();   // drains vmcnt before LDS reads
#pragma unroll
    for (int kk = 0; kk < 64; kk += 32) {
      short8 af = *(const short8*)&As[wm * 16 + l16][kk + quad * 8];
      short8 bfr[2];
#pragma unroll
      for (int j = 0; j < 2; ++j)
        bfr[j] = *(const short8*)&Bs[wn * 32 + j * 16 + l16][kk + quad * 8];
#pragma unroll
      for (int j = 0; j < 2; ++j)
        acc[j] = __builtin_amdgcn_mfma_f32_16x16x32_bf16(af, bfr[j], acc[j], 0, 0, 0);
    }
    __syncthreads();
  }

  {
    int m = m0 + wm * 16 + quad * 4;
    int b = m >> 10, l = m & 1023;
#pragma unroll
    for (int j = 0; j < 2; ++j) {
      int n = n0 + wn * 32 + j * 16 + l16;
      size_t o = (size_t)b * (DIMC * LSEQ) + (size_t)n * LSEQ + l;
      f32x4 xv = *(const f32x4*)(X + o);
      f32x4 rv = acc[j] + xv;
      *(f32x4*)(C + o) = rv;
    }
  }
}

// ---------------------------------------------------------------------------
// Fused conv + SiLU + xproj + dt (MFMA).
// m-tile 16, grid 512 (2 blocks/CU co-resident = 2 waves/SIMD).
// xproj uses TWO independent MFMA accumulator chains (k halves) for 2x ILP.
__global__ __launch_bounds__(256) void conv_xproj_dt(
    const unsigned short* __restrict__ xzb,
    const float* __restrict__ conv_w,
    const float* __restrict__ conv_b,
    const unsigned short* __restrict__ Wxpb,
    const unsigned short* __restrict__ Wdtb,
    const float* __restrict__ b_dt,
    float* __restrict__ dbcBC,
    unsigned int* __restrict__ dtu) {
  __shared__ unsigned short sxz[19][512];       // 16 rows + 3 halo
  __shared__ unsigned short su[16][512 + 8];
  __shared__ unsigned short sdbc[16][40];
  const int m0 = blockIdx.x * 16;
  const int l0 = m0 & 1023;
  const int tid = threadIdx.x, lane = tid & 63, w = tid >> 6;
  const int quad = lane >> 4, l16 = lane & 15;

  // Stage the xz u-half tile with halo: 19*64 = 1216 chunks of 8 bf16.
#pragma unroll
  for (int q = 0; q < 5; ++q) {
    int id = q * 256 + tid;
    if (id < 19 * 64) {
      int rr = id >> 6, c8 = id & 63;
      uint4 v; v.x = 0u; v.y = 0u; v.z = 0u; v.w = 0u;
      if (l0 - 3 + rr >= 0)
        v = *(const uint4*)(xzb + (size_t)(m0 - 3 + rr) * 1024 + c8 * 8);
      *(uint4*)&sxz[rr][c8 * 8] = v;
    }
  }
  __syncthreads();

  // conv(k=4) + bias + SiLU -> su (32 outputs/thread, coalesced in c).
#pragma unroll 4
  for (int q = 0; q < 32; ++q) {
    int idx = q * 256 + tid;
    int r = idx >> 9, c = idx & 511;
    float4 wv = *(const float4*)(conv_w + c * 4);
    float acc = conv_b[c];
    acc = fmaf(bf2f(sxz[r + 0][c]), wv.x, acc);
    acc = fmaf(bf2f(sxz[r + 1][c]), wv.y, acc);
    acc = fmaf(bf2f(sxz[r + 2][c]), wv.z, acc);
    acc = fmaf(bf2f(sxz[r + 3][c]), wv.w, acc);
    float u = acc / (1.f + __expf(-acc));
    su[r][c] = f2bf(u);
  }
  __syncthreads();

  // xproj MFMA: A-frags from su, B-frags from global (L2-hot).
  // Two independent accumulator chains over k halves -> 2x MFMA ILP.
  f32x4 acc0 = (f32x4){0.f, 0.f, 0.f, 0.f};
  f32x4 acc1 = (f32x4){0.f, 0.f, 0.f, 0.f};
#pragma unroll 4
  for (int k0 = 0; k0 < 256; k0 += 32) {
    short8 afA = *(const short8*)&su[l16][k0 + quad * 8];
    short8 bfA = *(const short8*)(Wxpb + (size_t)(w * 16 + l16) * 512 + k0 + quad * 8);
    acc0 = __builtin_amdgcn_mfma_f32_16x16x32_bf16(afA, bfA, acc0, 0, 0, 0);
    short8 afB = *(const short8*)&su[l16][256 + k0 + quad * 8];
    short8 bfB = *(const short8*)(Wxpb + (size_t)(w * 16 + l16) * 512 + 256 + k0 + quad * 8);
    acc1 = __builtin_amdgcn_mfma_f32_16x16x32_bf16(afB, bfB, acc1, 0, 0, 0);
  }
  f32x4 acc = acc0 + acc1;
  // Persist only B (n=16..31) and C (n=32..47) columns.
  if (w == 1 || w == 2) {
#pragma unroll
    for (int r = 0; r < 4; ++r)
      dbcBC[(size_t)(m0 + quad * 4 + r) * 32 + (w - 1) * 16 + l16] = acc[r];
  }
  if (w < 2) {
#pragma unroll
    for (int r = 0; r < 4; ++r)
      sdbc[quad * 4 + r][w * 16 + l16] = f2bf(acc[r]);
  }
  __syncthreads();

  // dt MFMA + softplus + dtu pack (u pulled from su).
  short8 af0 = *(const short8*)&sdbc[l16][quad * 8];
#pragma unroll
  for (int jn = 0; jn < 8; ++jn) {
    const int n0 = w * 128 + jn * 16;
    short8 bf = *(const short8*)(Wdtb + (size_t)(n0 + l16) * 32 + quad * 8);
    f32x4 a0 = (f32x4){0.f, 0.f, 0.f, 0.f};
    a0 = __builtin_amdgcn_mfma_f32_16x16x32_bf16(af0, bf, a0, 0, 0, 0);
    const float bd = b_dt[n0 + l16];
#pragma unroll
    for (int r = 0; r < 4; ++r) {
      int lr0 = quad * 4 + r;
      float v = a0[r] + bd;
      float sp = (v > 20.f) ? v : log1pf(__expf(v));
      unsigned int u0 = (unsigned int)su[lr0][n0 + l16];
      dtu[(size_t)(m0 + lr0) * DI + n0 + l16] = u0 | ((unsigned int)f2bf(sp) << 16);
    }
  }
}

// ---------------------------------------------------------------------------
// Chunked selective scan, (d,s) LDS-staged layout.
// Pass 1: local scan from h=0 -> hend, sum dt. Grid (BATCH, 32, NC).
__global__ __launch_bounds__(256) void scan_pass1(const unsigned int* __restrict__ dtu,
                                                  const float* __restrict__ dbcBC,
                                                  const float* __restrict__ A_log,
                                                  float* __restrict__ hend,
                                                  float* __restrict__ Ssum) {
  const int bb = blockIdx.x, dblk = blockIdx.y, cc = blockIdx.z;
  const int tid = threadIdx.x;
  const int di = tid >> 4, s = tid & 15;
  const int d = dblk * 16 + di;
  const float Ads = -__expf(A_log[d * DS + s]);

  __shared__ float2 sdu[CHUNK][18];   // (dt, u); pad -> <=2-way on b128 writes
  __shared__ float  sB[CHUNK][17];
  {
    const int t0 = cc * CHUNK;
    int lin = tid * 4;                 // 4 elems per thread
    int tt = lin >> 4, dd = lin & 15;  // dd in {0,4,8,12}
    size_t m = (size_t)bb * LSEQ + t0 + tt;
    uint4 du4 = *(const uint4*)(dtu + m * DI + dblk * 16 + dd);
    f32x4 a, b2;
    a[0]  = bf2f((unsigned short)(du4.x >> 16)); a[1]  = bf2f((unsigned short)(du4.x & 0xffff));
    a[2]  = bf2f((unsigned short)(du4.y >> 16)); a[3]  = bf2f((unsigned short)(du4.y & 0xffff));
    b2[0] = bf2f((unsigned short)(du4.z >> 16)); b2[1] = bf2f((unsigned short)(du4.z & 0xffff));
    b2[2] = bf2f((unsigned short)(du4.w >> 16)); b2[3] = bf2f((unsigned short)(du4.w & 0xffff));
    *(f32x4*)&sdu[tt][dd]     = a;
    *(f32x4*)&sdu[tt][dd + 2] = b2;
    f32x4 Bv = *(const f32x4*)(dbcBC + m * 32 + dd);
    *(f32x4*)&sB[tt][dd] = Bv;
  }
  __syncthreads();
  float h = 0.f, dtsum = 0.f;
#pragma unroll 4
  for (int tt = 0; tt < CHUNK; ++tt) {
    float2 du = sdu[tt][di];
    float Bv  = sB[tt][s];
    h = fmaf(__expf(du.x * Ads), h, du.x * du.y * Bv);
    dtsum += du.x;
  }
  size_t ci = ((size_t)(bb * NC + cc) * DI + d);
  hend[ci * DS + s] = h;
  if (s == 0) Ssum[ci] = dtsum;
}

// Pass 2: sequential combine over chunks -> h_in per chunk. (tiny, 256 blocks)
__global__ __launch_bounds__(256) void scan_pass2(const float* __restrict__ A_log,
                                                  const float* __restrict__ hend,
                                                  const float* __restrict__ Ssum,
                                                  float* __restrict__ hin) {
  const int bb = blockIdx.x, dblk = blockIdx.y;
  const int tid = threadIdx.x;
  const int di = tid >> 4, s = tid & 15;
  const int d = dblk * 16 + di;
  const float Ads = -__expf(A_log[d * DS + s]);
  float h = 0.f;
  for (int cc = 0; cc < NC; ++cc) {
    size_t ci = ((size_t)(bb * NC + cc) * DI + d);
    hin[ci * DS + s] = h;
    h = fmaf(__expf(Ads * Ssum[ci]), h, hend[ci * DS + s]);
  }
}

// Pass 3: re-run each chunk from true h_in, fused gate epilogue -> yb (bf16).
__global__ __launch_bounds__(256) void scan_pass3(const unsigned int* __restrict__ dtu,
                                                  const float* __restrict__ dbcBC,
                                                  const unsigned short* __restrict__ xzb,
                                                  const float* __restrict__ A_log,
                                                  const float* __restrict__ D_skip,
                                                  const float* __restrict__ hin,
                                                  unsigned short* __restrict__ yb) {
  const int bb = blockIdx.x, dblk = blockIdx.y, cc = blockIdx.z;
  const int tid = threadIdx.x;
  const int di = tid >> 4, s = tid & 15;
  const int d = dblk * 16 + di;
  const float Ads = -__expf(A_log[d * DS + s]);

  __shared__ float2 sdu[CHUNK][18];   // (dt, u)
  __shared__ float2 sBC[CHUNK][18];   // (B, C)
  __shared__ float  sy[CHUNK][16];
  const int t0 = cc * CHUNK;
  const size_t mbase = (size_t)bb * LSEQ + t0;
  {
    int lin = tid * 4;
    int tt = lin >> 4, dd = lin & 15;   // dd in {0,4,8,12}
    size_t m = mbase + tt;
    uint4 du4 = *(const uint4*)(dtu + m * DI + dblk * 16 + dd);
    f32x4 a, b2;
    a[0]  = bf2f((unsigned short)(du4.x >> 16)); a[1]  = bf2f((unsigned short)(du4.x & 0xffff));
    a[2]  = bf2f((unsigned short)(du4.y >> 16)); a[3]  = bf2f((unsigned short)(du4.y & 0xffff));
    b2[0] = bf2f((unsigned short)(du4.z >> 16)); b2[1] = bf2f((unsigned short)(du4.z & 0xffff));
    b2[2] = bf2f((unsigned short)(du4.w >> 16)); b2[3] = bf2f((unsigned short)(du4.w & 0xffff));
    *(f32x4*)&sdu[tt][dd]     = a;
    *(f32x4*)&sdu[tt][dd + 2] = b2;
    f32x4 Bv = *(const f32x4*)(dbcBC + m * 32 + dd);
    f32x4 Cv = *(const f32x4*)(dbcBC + m * 32 + 16 + dd);
    f32x4 p0, p1;
    p0[0] = Bv[0]; p0[1] = Cv[0]; p0[2] = Bv[1]; p0[3] = Cv[1];
    p1[0] = Bv[2]; p1[1] = Cv[2]; p1[2] = Bv[3]; p1[3] = Cv[3];
    *(f32x4*)&sBC[tt][dd]     = p0;
    *(f32x4*)&sBC[tt][dd + 2] = p1;
  }
  __syncthreads();
  float h = hin[((size_t)(bb * NC + cc) * DI + d) * DS + s];
#pragma unroll 4
  for (int tt = 0; tt < CHUNK; ++tt) {
    float2 du = sdu[tt][di];
    float2 bc = sBC[tt][s];
    h = fmaf(__expf(du.x * Ads), h, du.x * du.y * bc.x);
    float v = dpp_sum16(h * bc.y);
    if (s == 0) sy[tt][di] = v;
  }
  __syncthreads();
#pragma unroll
  for (int q = 0; q < 4; ++q) {
    int lin = q * 256 + tid;
    int tt = lin >> 4, dd = lin & 15;
    size_t m = mbase + tt;
    float z = bf2f(xzb[m * 1024 + DI + dblk * 16 + dd]);   // direct global, coalesced
    float yv = sy[tt][dd] + sdu[tt][dd].y * D_skip[dblk * 16 + dd];
    yv *= z / (1.f + __expf(-z));
    yb[m * DI + dblk * 16 + dd] = f2bf(yv);
  }
}

// ---------------------------------------------------------------------------
extern "C" void kernel_launch(void* const* d_in, const int* in_sizes, int n_in,
                              void* d_out, int out_size, void* d_ws, size_t ws_size,
                              hipStream_t stream) {
  const float* x       = (const float*)d_in[0];
  const float* ln_g    = (const float*)d_in[1];
  const float* ln_b    = (const float*)d_in[2];
  const float* W_in    = (const float*)d_in[3];
  const float* conv_w  = (const float*)d_in[4];
  const float* conv_b  = (const float*)d_in[5];
  const float* W_xproj = (const float*)d_in[6];
  const float* W_dt    = (const float*)d_in[7];
  const float* b_dt    = (const float*)d_in[8];
  const float* A_log   = (const float*)d_in[9];
  const float* D_skip  = (const float*)d_in[10];
  const float* W_out   = (const float*)d_in[11];
  float* out = (float*)d_out;

  // Workspace layout
  float* ws    = (float*)d_ws;
  float* dbcBC = ws;                                    //   262,144 f
  float* hend  = dbcBC + (size_t)MROWS * 32;            // 1,048,576 f
  float* hin   = hend + (size_t)BATCH * NC * DI * DS;   // 1,048,576 f
  float* Ssum  = hin  + (size_t)BATCH * NC * DI * DS;   //    65,536 f
  unsigned int* dtu = (unsigned int*)(Ssum + (size_t)BATCH * NC * DI); // 4,194,304 u32
  unsigned short* xzb  = (unsigned short*)(dtu + (size_t)MROWS * DI); // 8,388,608 us
  unsigned short* yb   = xzb + (size_t)MROWS * 1024;    // 4,194,304 us
  unsigned short* xnb  = yb;   // alias: xnb dead before pass3 writes yb
  unsigned short* Wib  = yb  + (size_t)MROWS * DI;      // 262,144 us
  unsigned short* Wob  = Wib + (size_t)DIMC * 1024;     // 131,072 us
  unsigned short* Wxpb = Wob + (size_t)DI * DIMC;       //  32,768 us
  unsigned short* Wdtb = Wxpb + (size_t)64 * 512;       //  16,384 us

  // 0. prologue: weight prep + LayerNorm (256 LN blocks), one launch
  prologue<<<832, 256, 0, stream>>>(W_in, W_out, W_xproj, W_dt, x, ln_g, ln_b,
                                    Wib, Wob, Wxpb, Wdtb, xnb);

  // 1. xzb = bf16(xn @ W_in)   (8192x1024x256, 128x64 tile, 1024 blocks)
  gemm_bf16_m128n64<<<dim3(1024 / 64, MROWS / 128), 256, 0, stream>>>(
      xnb, Wib, xzb, MROWS, 1024, DIMC);

  // 2. fused: conv+SiLU (in LDS) ; dbcBC = (B|C) of u @ W_xproj ; dtu pack
  conv_xproj_dt<<<MROWS / 16, 256, 0, stream>>>(xzb, conv_w, conv_b,
                                                Wxpb, Wdtb, b_dt, dbcBC, dtu);

  // 3. chunked selective scan (3-pass form)
  dim3 gp13(BATCH, DI / 16, NC);
  dim3 gp2(BATCH, DI / 16);
  scan_pass1<<<gp13, 256, 0, stream>>>(dtu, dbcBC, A_log, hend, Ssum);
  scan_pass2<<<gp2, 256, 0, stream>>>(A_log, hend, Ssum, hin);
  scan_pass3<<<gp13, 256, 0, stream>>>(dtu, dbcBC, xzb, A_log, D_skip, hin, yb);

  // 4. out = yb @ W_out (32x64 tile, 1024 blocks = 4/CU, +x residual)
  gemm_bf16_m32n64<<<dim3(DIMC / 64, MROWS / 32), 256, 0, stream>>>(
      yb, Wob, out, MROWS, DIMC, DI, x);
}